// Round 14
// baseline (2865.834 us; speedup 1.0000x reference)
//
#include <hip/hip_runtime.h>
#include <hip/hip_bf16.h>

typedef __bf16 bf16_t;
typedef __attribute__((ext_vector_type(8))) __bf16 bf16x8;
typedef __attribute__((ext_vector_type(4))) float f32x4;

#define D_MODEL 1024
#define H_DIM   4096
#define VOCAB   32000
#define NBLK    4
#define BATCH   2
#define SEQ     2048
#define NTOK    (BATCH*SEQ)
#define SCALE_QK (1.0f/32.0f)
#define LN_EPS  1e-5f

#define BM 128
#define BN 128
#define BK 32
#define GROUP_M 8
#define NXCD 8

// async global->LDS, 16B per lane, LDS dest = wave-uniform base + lane*16
__device__ __forceinline__ void gload16(const bf16_t* g, bf16_t* l) {
    __builtin_amdgcn_global_load_lds(
        (const __attribute__((address_space(1))) void*)g,
        (__attribute__((address_space(3))) void*)l,
        16, 0, 0);
}

// ---------------- embedding: x = tok_emb[tok] + pos_emb[s] ----------------
__global__ void embed_kernel(const int* __restrict__ tokens,
                             const float* __restrict__ tok_emb,
                             const float* __restrict__ pos_emb,
                             float* __restrict__ x, bf16_t* __restrict__ xb) {
    int row = blockIdx.x;            // b*SEQ + s
    int s   = row & (SEQ - 1);
    int tok = tokens[row];
    const float* te = tok_emb + (size_t)tok * D_MODEL;
    const float* pe = pos_emb + (size_t)s * D_MODEL;
    int d = threadIdx.x * 4;         // 256 threads * 4 = 1024
    float4 a = *(const float4*)(te + d);
    float4 p = *(const float4*)(pe + d);
    float4 r; r.x = a.x + p.x; r.y = a.y + p.y; r.z = a.z + p.z; r.w = a.w + p.w;
    *(float4*)(x + (size_t)row * D_MODEL + d) = r;
    union { bf16_t h[4]; unsigned long long u; } pk;
    pk.h[0] = (bf16_t)r.x; pk.h[1] = (bf16_t)r.y; pk.h[2] = (bf16_t)r.z; pk.h[3] = (bf16_t)r.w;
    *(unsigned long long*)(xb + (size_t)row * D_MODEL + d) = pk.u;
}

// ---------------- transpose + fp32->bf16: WT[n][k] = W[k][n] ----------------
__global__ void transpose_cvt_kernel(const float* __restrict__ W, bf16_t* __restrict__ WT,
                                     int K, int N) {
    __shared__ float t[32][33];
    int k0 = blockIdx.y * 32, n0 = blockIdx.x * 32;
    int tx = threadIdx.x, ty = threadIdx.y;   // 32 x 8
    for (int i = ty; i < 32; i += 8) t[i][tx] = W[(size_t)(k0 + i) * N + n0 + tx];
    __syncthreads();
    for (int i = ty; i < 32; i += 8) WT[(size_t)(n0 + i) * K + k0 + tx] = (bf16_t)t[tx][i];
}

// ================= 256x256 8-wave pipelined GEMM, 4-phase schedule =================
// Race-fixed tail drain; batch via blockIdx.y; flag4 causal K-limit.
// flags: 1=relu, 4=causal K-limit, 8=store Cb transposed
__global__ __launch_bounds__(512)
void gemm256_kernel(const bf16_t* __restrict__ A, const bf16_t* __restrict__ B,
                    const float* __restrict__ bias,
                    float* __restrict__ Cf, bf16_t* __restrict__ Cb,
                    int M, int N, int K, int ldb, int ldct, float scale, int flags,
                    long bsA, long bsB, long bsC) {
    extern __shared__ char lds[];     // [0,64K): A slots 0/1; [64K,160K): B slots 0/1/2
    const int bidx = blockIdx.y;
    A += (size_t)bidx * bsA;
    B += (size_t)bidx * bsB;
    if (Cf) Cf += (size_t)bidx * bsC;
    if (Cb) Cb += (size_t)bidx * bsC;

    const int nTM = M >> 8, nTN = N >> 8;
    const int nwg = nTM * nTN;
    int orig = blockIdx.x;
    const int q = nwg / NXCD, r = nwg % NXCD;
    const int xcd = orig % NXCD, idx = orig / NXCD;
    int wgid = (xcd < r ? xcd * (q + 1) : r * (q + 1) + (xcd - r) * q) + idx;
    const int tpg = GROUP_M * nTN;
    const int g   = wgid / tpg;
    const int rem = wgid % tpg;
    int gm = nTM - g * GROUP_M; if (gm > GROUP_M) gm = GROUP_M;
    const int mt = g * GROUP_M + rem % gm;
    const int nt = rem / gm;
    const int m0 = mt << 8, n0 = nt << 8;
    const int Keff = (flags & 4) ? ((K < m0 + 256) ? K : (m0 + 256)) : K;

    const int tid  = threadIdx.x;
    const int lane = tid & 63;
    const int wid  = tid >> 6;
    const int wr   = wid >> 2;        // 0..1
    const int wc   = wid & 3;         // 0..3

    const int srow = tid >> 3;                         // 0..63
    const int scol = ((tid & 7) ^ (srow & 7)) << 3;    // element col, swizzled
    const bf16_t* Ag = A + (size_t)(m0 + srow) * K   + scol;
    const bf16_t* Bg = B + (size_t)(n0 + srow) * ldb + scol;
    char* ldsw = lds + wid * 1024;

    const int lr  = lane & 15;
    const int kgb = (lane >> 4) * 16;
    const int xv  = (lane & 7) << 4;
    const int aoff = (wr * 128 + lr) * 128;
    const int boff = (wc * 64  + lr) * 128;

    f32x4 acc[8][4];
#pragma unroll
    for (int i = 0; i < 8; ++i)
#pragma unroll
        for (int j = 0; j < 4; ++j) acc[i][j] = (f32x4){0.f, 0.f, 0.f, 0.f};

    const int NT = Keff >> 6;

    auto stageA = [&](int t) {
#pragma unroll
        for (int j = 0; j < 4; ++j)
            gload16(Ag + (size_t)j * 64 * K + t * 64,
                    (bf16_t*)(ldsw + (t & 1) * 32768 + j * 8192));
    };
    auto stageBj = [&](int t, int j) {
        gload16(Bg + (size_t)j * 64 * ldb + t * 64,
                (bf16_t*)(ldsw + 65536 + (t % 3) * 32768 + j * 8192));
    };

    stageBj(0,0); stageBj(0,1); stageBj(0,2); stageBj(0,3); stageA(0);
    if (NT > 1) { stageBj(1,0); stageBj(1,1); stageBj(1,2); stageBj(1,3); stageA(1); }
    asm volatile("s_waitcnt vmcnt(8)" ::: "memory");
    __builtin_amdgcn_s_barrier();

    for (int s = 0; s < NT; ++s) {
        const char* Abase = lds + (s & 1) * 32768 + aoff;
        const char* Bbase = lds + 65536 + (s % 3) * 32768 + boff;
        const bool pf = (s + 2 < NT);
        const int klo = kgb ^ xv;
        const int khi = (64 + kgb) ^ xv;

        bf16x8 av[4], aw[4], bv[4];

        // phase 0
#pragma unroll
        for (int i = 0; i < 4; ++i) av[i] = *(const bf16x8*)(Abase + i * 2048 + klo);
#pragma unroll
        for (int j = 0; j < 4; ++j) bv[j] = *(const bf16x8*)(Bbase + j * 2048 + klo);
        if (pf) { stageBj(s + 2, 0); stageBj(s + 2, 1); }
        __builtin_amdgcn_s_barrier();
        asm volatile("s_waitcnt lgkmcnt(0)" ::: "memory");
        __builtin_amdgcn_sched_barrier(0);
        __builtin_amdgcn_s_setprio(1);
#pragma unroll
        for (int i = 0; i < 4; ++i)
#pragma unroll
            for (int j = 0; j < 4; ++j)
                acc[i][j] = __builtin_amdgcn_mfma_f32_16x16x32_bf16(av[i], bv[j], acc[i][j], 0, 0, 0);
        __builtin_amdgcn_s_setprio(0);
        __builtin_amdgcn_s_barrier();

        // phase 1
#pragma unroll
        for (int i = 0; i < 4; ++i) aw[i] = *(const bf16x8*)(Abase + (4 + i) * 2048 + klo);
        if (pf) { stageBj(s + 2, 2); stageBj(s + 2, 3); }
        __builtin_amdgcn_s_barrier();
        asm volatile("s_waitcnt lgkmcnt(0)" ::: "memory");
        __builtin_amdgcn_sched_barrier(0);
        __builtin_amdgcn_s_setprio(1);
#pragma unroll
        for (int i = 0; i < 4; ++i)
#pragma unroll
            for (int j = 0; j < 4; ++j)
                acc[4 + i][j] = __builtin_amdgcn_mfma_f32_16x16x32_bf16(aw[i], bv[j], acc[4 + i][j], 0, 0, 0);
        __builtin_amdgcn_s_setprio(0);
        __builtin_amdgcn_s_barrier();

        // phase 2
#pragma unroll
        for (int i = 0; i < 4; ++i) av[i] = *(const bf16x8*)(Abase + i * 2048 + khi);
#pragma unroll
        for (int j = 0; j < 4; ++j) bv[j] = *(const bf16x8*)(Bbase + j * 2048 + khi);
        __builtin_amdgcn_s_barrier();
        asm volatile("s_waitcnt lgkmcnt(0)" ::: "memory");
        __builtin_amdgcn_sched_barrier(0);
        __builtin_amdgcn_s_setprio(1);
#pragma unroll
        for (int i = 0; i < 4; ++i)
#pragma unroll
            for (int j = 0; j < 4; ++j)
                acc[i][j] = __builtin_amdgcn_mfma_f32_16x16x32_bf16(av[i], bv[j], acc[i][j], 0, 0, 0);
        __builtin_amdgcn_s_setprio(0);
        __builtin_amdgcn_s_barrier();

        // phase 3
#pragma unroll
        for (int i = 0; i < 4; ++i) aw[i] = *(const bf16x8*)(Abase + (4 + i) * 2048 + khi);
        asm volatile("s_waitcnt lgkmcnt(0)" ::: "memory");
        __builtin_amdgcn_sched_barrier(0);
        __builtin_amdgcn_s_barrier();
        if (pf) stageA(s + 2);
        __builtin_amdgcn_s_setprio(1);
#pragma unroll
        for (int i = 0; i < 4; ++i)
#pragma unroll
            for (int j = 0; j < 4; ++j)
                acc[4 + i][j] = __builtin_amdgcn_mfma_f32_16x16x32_bf16(aw[i], bv[j], acc[4 + i][j], 0, 0, 0);
        __builtin_amdgcn_s_setprio(0);
        if (pf) asm volatile("s_waitcnt vmcnt(8)" ::: "memory");
        else    asm volatile("s_waitcnt vmcnt(0)" ::: "memory");
        __builtin_amdgcn_sched_barrier(0);
        __builtin_amdgcn_s_barrier();
    }

    const int r0 = (lane >> 4) * 4;
    const int cc = lane & 15;
#pragma unroll
    for (int i = 0; i < 8; ++i) {
        const int growb = m0 + wr * 128 + i * 16 + r0;
#pragma unroll
        for (int j = 0; j < 4; ++j) {
            const int gcol = n0 + wc * 64 + j * 16 + cc;
            const float bv2 = bias ? bias[gcol] : 0.f;
#pragma unroll
            for (int r2 = 0; r2 < 4; ++r2) {
                const int grow = growb + r2;
                float v = acc[i][j][r2] * scale + bv2;
                if (flags & 1) v = fmaxf(v, 0.f);
                if (Cf) Cf[(size_t)grow * N + gcol] = v;
                if (Cb) {
                    if (flags & 8) Cb[(size_t)gcol * ldct + grow] = (bf16_t)v;
                    else           Cb[(size_t)grow * N + gcol]   = (bf16_t)v;
                }
            }
        }
    }
}

// ============ 256x128 variant (BN=128) — attnV: halves per-WG critical path ============
// Same 4-phase schedule; B tri-buf 3x16KB at [64K,112K); 6 loads/K-tile -> vmcnt(6).
// flags: 4=causal K-limit. Output Cb non-transposed.
__global__ __launch_bounds__(512)
void gemm256n_kernel(const bf16_t* __restrict__ A, const bf16_t* __restrict__ B,
                     float* __restrict__ Cf, bf16_t* __restrict__ Cb,
                     int M, int N, int K, int ldb, float scale, int flags,
                     long bsA, long bsB, long bsC) {
    extern __shared__ char lds[];     // [0,64K): A slots 0/1; [64K,112K): B slots 0/1/2
    const int bidx = blockIdx.y;
    A += (size_t)bidx * bsA;
    B += (size_t)bidx * bsB;
    if (Cf) Cf += (size_t)bidx * bsC;
    if (Cb) Cb += (size_t)bidx * bsC;

    const int nTM = M >> 8, nTN = N >> 7;
    const int nwg = nTM * nTN;
    int orig = blockIdx.x;
    const int q = nwg / NXCD, r = nwg % NXCD;
    const int xcd = orig % NXCD, idx = orig / NXCD;
    int wgid = (xcd < r ? xcd * (q + 1) : r * (q + 1) + (xcd - r) * q) + idx;
    const int tpg = GROUP_M * nTN;
    const int g   = wgid / tpg;
    const int rem = wgid % tpg;
    int gm = nTM - g * GROUP_M; if (gm > GROUP_M) gm = GROUP_M;
    const int mt = g * GROUP_M + rem % gm;
    const int nt = rem / gm;
    const int m0 = mt << 8, n0 = nt << 7;
    const int Keff = (flags & 4) ? ((K < m0 + 256) ? K : (m0 + 256)) : K;

    const int tid  = threadIdx.x;
    const int lane = tid & 63;
    const int wid  = tid >> 6;
    const int wr   = wid >> 2;        // 0..1 -> A rows wr*128
    const int wc   = wid & 3;         // 0..3 -> C cols wc*32

    const int srow = tid >> 3;                         // 0..63
    const int scol = ((tid & 7) ^ (srow & 7)) << 3;    // swizzled source col
    const bf16_t* Ag = A + (size_t)(m0 + srow) * K   + scol;
    const bf16_t* Bg = B + (size_t)(n0 + srow) * ldb + scol;
    char* ldsw = lds + wid * 1024;

    const int lr  = lane & 15;
    const int kgb = (lane >> 4) * 16;
    const int xv  = (lane & 7) << 4;
    const int aoff = (wr * 128 + lr) * 128;
    const int boff = (wc * 32  + lr) * 128;

    f32x4 acc[8][2];
#pragma unroll
    for (int i = 0; i < 8; ++i)
#pragma unroll
        for (int j = 0; j < 2; ++j) acc[i][j] = (f32x4){0.f, 0.f, 0.f, 0.f};

    const int NT = Keff >> 6;

    auto stageA = [&](int t) {
#pragma unroll
        for (int j = 0; j < 4; ++j)
            gload16(Ag + (size_t)j * 64 * K + t * 64,
                    (bf16_t*)(ldsw + (t & 1) * 32768 + j * 8192));
    };
    auto stageBh = [&](int t, int h) {       // B half h: rows h*64..h*64+63
        gload16(Bg + (size_t)h * 64 * ldb + t * 64,
                (bf16_t*)(ldsw + 65536 + (t % 3) * 16384 + h * 8192));
    };

    stageBh(0,0); stageBh(0,1); stageA(0);
    if (NT > 1) { stageBh(1,0); stageBh(1,1); stageA(1); }
    asm volatile("s_waitcnt vmcnt(6)" ::: "memory");
    __builtin_amdgcn_s_barrier();

    for (int s = 0; s < NT; ++s) {
        const char* Abase = lds + (s & 1) * 32768 + aoff;
        const char* Bbase = lds + 65536 + (s % 3) * 16384 + boff;
        const bool pf = (s + 2 < NT);
        const int klo = kgb ^ xv;
        const int khi = (64 + kgb) ^ xv;

        bf16x8 av[4], aw[4], bv[2];

        // phase 0: rows 0-3, k-half 0
#pragma unroll
        for (int i = 0; i < 4; ++i) av[i] = *(const bf16x8*)(Abase + i * 2048 + klo);
#pragma unroll
        for (int j = 0; j < 2; ++j) bv[j] = *(const bf16x8*)(Bbase + j * 2048 + klo);
        if (pf) stageBh(s + 2, 0);
        __builtin_amdgcn_s_barrier();
        asm volatile("s_waitcnt lgkmcnt(0)" ::: "memory");
        __builtin_amdgcn_sched_barrier(0);
        __builtin_amdgcn_s_setprio(1);
#pragma unroll
        for (int i = 0; i < 4; ++i)
#pragma unroll
            for (int j = 0; j < 2; ++j)
                acc[i][j] = __builtin_amdgcn_mfma_f32_16x16x32_bf16(av[i], bv[j], acc[i][j], 0, 0, 0);
        __builtin_amdgcn_s_setprio(0);
        __builtin_amdgcn_s_barrier();

        // phase 1: rows 4-7, k-half 0
#pragma unroll
        for (int i = 0; i < 4; ++i) aw[i] = *(const bf16x8*)(Abase + (4 + i) * 2048 + klo);
        if (pf) stageBh(s + 2, 1);
        __builtin_amdgcn_s_barrier();
        asm volatile("s_waitcnt lgkmcnt(0)" ::: "memory");
        __builtin_amdgcn_sched_barrier(0);
        __builtin_amdgcn_s_setprio(1);
#pragma unroll
        for (int i = 0; i < 4; ++i)
#pragma unroll
            for (int j = 0; j < 2; ++j)
                acc[4 + i][j] = __builtin_amdgcn_mfma_f32_16x16x32_bf16(aw[i], bv[j], acc[4 + i][j], 0, 0, 0);
        __builtin_amdgcn_s_setprio(0);
        __builtin_amdgcn_s_barrier();

        // phase 2: rows 0-3, k-half 1
#pragma unroll
        for (int i = 0; i < 4; ++i) av[i] = *(const bf16x8*)(Abase + i * 2048 + khi);
#pragma unroll
        for (int j = 0; j < 2; ++j) bv[j] = *(const bf16x8*)(Bbase + j * 2048 + khi);
        __builtin_amdgcn_s_barrier();
        asm volatile("s_waitcnt lgkmcnt(0)" ::: "memory");
        __builtin_amdgcn_sched_barrier(0);
        __builtin_amdgcn_s_setprio(1);
#pragma unroll
        for (int i = 0; i < 4; ++i)
#pragma unroll
            for (int j = 0; j < 2; ++j)
                acc[i][j] = __builtin_amdgcn_mfma_f32_16x16x32_bf16(av[i], bv[j], acc[i][j], 0, 0, 0);
        __builtin_amdgcn_s_setprio(0);
        __builtin_amdgcn_s_barrier();

        // phase 3: rows 4-7, k-half 1; stage A(s+2) after all A-reads done
#pragma unroll
        for (int i = 0; i < 4; ++i) aw[i] = *(const bf16x8*)(Abase + (4 + i) * 2048 + khi);
        asm volatile("s_waitcnt lgkmcnt(0)" ::: "memory");
        __builtin_amdgcn_sched_barrier(0);
        __builtin_amdgcn_s_barrier();
        if (pf) stageA(s + 2);
        __builtin_amdgcn_s_setprio(1);
#pragma unroll
        for (int i = 0; i < 4; ++i)
#pragma unroll
            for (int j = 0; j < 2; ++j)
                acc[4 + i][j] = __builtin_amdgcn_mfma_f32_16x16x32_bf16(aw[i], bv[j], acc[4 + i][j], 0, 0, 0);
        __builtin_amdgcn_s_setprio(0);
        if (pf) asm volatile("s_waitcnt vmcnt(6)" ::: "memory");
        else    asm volatile("s_waitcnt vmcnt(0)" ::: "memory");
        __builtin_amdgcn_sched_barrier(0);
        __builtin_amdgcn_s_barrier();
    }

    const int r0 = (lane >> 4) * 4;
    const int cc = lane & 15;
#pragma unroll
    for (int i = 0; i < 8; ++i) {
        const int growb = m0 + wr * 128 + i * 16 + r0;
#pragma unroll
        for (int j = 0; j < 2; ++j) {
            const int gcol = n0 + wc * 32 + j * 16 + cc;
#pragma unroll
            for (int r2 = 0; r2 < 4; ++r2) {
                const int grow = growb + r2;
                float v = acc[i][j][r2] * scale;
                if (Cf) Cf[(size_t)grow * N + gcol] = v;
                if (Cb) Cb[(size_t)grow * N + gcol] = (bf16_t)v;
            }
        }
    }
}

// ---------------- generic bf16 GEMM, B in [N,K] layout (128^2, m97-class) ----------------
// batched via blockIdx.y; flags: 1=relu, 2=causal tile skip, 4=causal K-limit, 8=Cb transposed
__global__ __launch_bounds__(256)
void gemm_bf16_kernel(const bf16_t* __restrict__ A, const bf16_t* __restrict__ B,
                      const float* __restrict__ bias, const float* __restrict__ resid,
                      float* __restrict__ Cf, bf16_t* __restrict__ Cb,
                      int M, int N, int K, int ldb, int ldct, float scale, int flags,
                      long bsA, long bsB, long bsC) {
    const int bidx = blockIdx.y;
    A += (size_t)bidx * bsA;
    B += (size_t)bidx * bsB;
    if (Cf) Cf += (size_t)bidx * bsC;
    if (Cb) Cb += (size_t)bidx * bsC;

    const int nTM = M / BM, nTN = N / BN;
    const int nwg = nTM * nTN;
    int orig = blockIdx.x;
    const int q = nwg / NXCD, r = nwg % NXCD;
    const int xcd = orig % NXCD, idx = orig / NXCD;
    int wgid = (xcd < r ? xcd * (q + 1) : r * (q + 1) + (xcd - r) * q) + idx;
    const int tpg = GROUP_M * nTN;
    const int g   = wgid / tpg;
    const int rem = wgid % tpg;
    int gm = nTM - g * GROUP_M; if (gm > GROUP_M) gm = GROUP_M;
    const int mt = g * GROUP_M + rem % gm;
    const int nt = rem / gm;

    const int m0 = mt * BM;
    const int n0 = nt * BN;
    if ((flags & 2) && n0 > m0 + BM - 1) return;
    const int Keff = (flags & 4) ? ((K < m0 + BM) ? K : (m0 + BM)) : K;

    __shared__ bf16_t As[BM * BK];
    __shared__ bf16_t Bs[BN * BK];

    const int tid  = threadIdx.x;
    const int lane = tid & 63;
    const int wid  = tid >> 6;
    const int wr   = (wid >> 1) * 64;
    const int wc   = (wid & 1) * 64;

    f32x4 acc[4][4];
#pragma unroll
    for (int i = 0; i < 4; ++i)
#pragma unroll
        for (int j = 0; j < 4; ++j)
            acc[i][j] = (f32x4){0.f, 0.f, 0.f, 0.f};

    const int r_in = lane >> 2;
    const int c8   = ((lane & 3) ^ ((lane >> 3) & 3)) * 8;
    const bf16_t* Ap = A + (size_t)(m0 + wid * 32 + r_in) * K   + c8;
    const bf16_t* Bp = B + (size_t)(n0 + wid * 32 + r_in) * ldb + c8;
    bf16_t* AsW = As + wid * 1024;
    bf16_t* BsW = Bs + wid * 1024;

    const int rsel = lane & 15;
    const int kg   = ((lane >> 4) ^ ((rsel >> 1) & 3)) * 8;

    for (int k0 = 0; k0 < Keff; k0 += BK) {
        gload16(Ap + k0,                    AsW);
        gload16(Ap + k0 + (size_t)16 * K,   AsW + 512);
        gload16(Bp + k0,                    BsW);
        gload16(Bp + k0 + (size_t)16 * ldb, BsW + 512);
        __syncthreads();

        bf16x8 af[4], bfr[4];
#pragma unroll
        for (int i = 0; i < 4; ++i) {
            af[i]  = *(const bf16x8*)&As[(wr + i * 16 + rsel) * BK + kg];
            bfr[i] = *(const bf16x8*)&Bs[(wc + i * 16 + rsel) * BK + kg];
        }
#pragma unroll
        for (int i = 0; i < 4; ++i)
#pragma unroll
            for (int j = 0; j < 4; ++j)
                acc[i][j] = __builtin_amdgcn_mfma_f32_16x16x32_bf16(af[i], bfr[j], acc[i][j], 0, 0, 0);
        __syncthreads();
    }

    const int r0 = (lane >> 4) * 4;
    const int cc = lane & 15;
#pragma unroll
    for (int i = 0; i < 4; ++i) {
        const int growb = m0 + wr + i * 16 + r0;
#pragma unroll
        for (int j = 0; j < 4; ++j) {
            const int gcol = n0 + wc + j * 16 + cc;
            const float bv = bias ? bias[gcol] : 0.f;
#pragma unroll
            for (int r2 = 0; r2 < 4; ++r2) {
                const int grow = growb + r2;
                float v = acc[i][j][r2] * scale + bv;
                if (resid) v += resid[(size_t)grow * N + gcol];
                if (flags & 1) v = fmaxf(v, 0.f);
                if (Cf) Cf[(size_t)grow * N + gcol] = v;
                if (Cb) {
                    if (flags & 8) Cb[(size_t)gcol * ldct + grow] = (bf16_t)v;
                    else           Cb[(size_t)grow * N + gcol]   = (bf16_t)v;
                }
            }
        }
    }
}

// ---------------- narrow-N GEMM: 128x64 tile, for Wo/Wdn (swizzled) ----------------
__global__ __launch_bounds__(256)
void gemm_nk_kernel(const bf16_t* __restrict__ A, const bf16_t* __restrict__ B,
                    const float* __restrict__ bias,
                    float* __restrict__ x, bf16_t* __restrict__ xb,
                    int M, int N, int K) {
    const int nTM = M / 128, nTN = N / 64;
    const int nwg = nTM * nTN;
    int orig = blockIdx.x;
    const int q = nwg / NXCD, r = nwg % NXCD;
    const int xcd = orig % NXCD, idx = orig / NXCD;
    int wgid = (xcd < r ? xcd * (q + 1) : r * (q + 1) + (xcd - r) * q) + idx;
    const int tpg = GROUP_M * nTN;
    const int g   = wgid / tpg;
    const int rem = wgid % tpg;
    int gm = nTM - g * GROUP_M; if (gm > GROUP_M) gm = GROUP_M;
    const int mt = g * GROUP_M + rem % gm;
    const int nt = rem / gm;
    const int m0 = mt * 128;
    const int n0 = nt * 64;

    __shared__ bf16_t As[128 * BK];
    __shared__ bf16_t Bs[64 * BK];

    const int tid  = threadIdx.x;
    const int lane = tid & 63;
    const int wid  = tid >> 6;
    const int wr   = (wid >> 1) * 64;   // A row base
    const int wc   = (wid & 1) * 32;    // B row (=C col) base

    f32x4 acc[4][2];
#pragma unroll
    for (int i = 0; i < 4; ++i)
#pragma unroll
        for (int j = 0; j < 2; ++j)
            acc[i][j] = (f32x4){0.f, 0.f, 0.f, 0.f};

    const int r_in = lane >> 2;
    const int c8   = ((lane & 3) ^ ((lane >> 3) & 3)) * 8;
    const bf16_t* Ap = A + (size_t)(m0 + wid * 32 + r_in) * K + c8;
    const bf16_t* Bp = B + (size_t)(n0 + wid * 16 + r_in) * K + c8;
    bf16_t* AsW = As + wid * 1024;   // 32 rows
    bf16_t* BsW = Bs + wid * 512;    // 16 rows

    const int rsel = lane & 15;
    const int kg   = ((lane >> 4) ^ ((rsel >> 1) & 3)) * 8;

    for (int k0 = 0; k0 < K; k0 += BK) {
        gload16(Ap + k0,                  AsW);
        gload16(Ap + k0 + (size_t)16 * K, AsW + 512);
        gload16(Bp + k0,                  BsW);
        __syncthreads();

        bf16x8 af[4], bfr[2];
#pragma unroll
        for (int i = 0; i < 4; ++i)
            af[i]  = *(const bf16x8*)&As[(wr + i * 16 + rsel) * BK + kg];
#pragma unroll
        for (int j = 0; j < 2; ++j)
            bfr[j] = *(const bf16x8*)&Bs[(wc + j * 16 + rsel) * BK + kg];
#pragma unroll
        for (int i = 0; i < 4; ++i)
#pragma unroll
            for (int j = 0; j < 2; ++j)
                acc[i][j] = __builtin_amdgcn_mfma_f32_16x16x32_bf16(af[i], bfr[j], acc[i][j], 0, 0, 0);
        __syncthreads();
    }

    const int r0 = (lane >> 4) * 4;
    const int cc = lane & 15;
#pragma unroll
    for (int i = 0; i < 4; ++i) {
        const int growb = m0 + wr + i * 16 + r0;
#pragma unroll
        for (int j = 0; j < 2; ++j) {
            const int gcol = n0 + wc + j * 16 + cc;
            const float bv = bias[gcol];
#pragma unroll
            for (int r2 = 0; r2 < 4; ++r2) {
                const int grow = growb + r2;
                const size_t off = (size_t)grow * N + gcol;
                float v = acc[i][j][r2] + bv + x[off];
                x[off]  = v;
                xb[off] = (bf16_t)v;
            }
        }
    }
}

// ---------------- causal softmax over k<=q, bf16 probs (zeros beyond) ----------------
__global__ void softmax_kernel(const float* __restrict__ sc, bf16_t* __restrict__ pr) {
    int row = blockIdx.x;                 // b*SEQ + q
    int q   = row & (SEQ - 1);
    const float* s = sc + (size_t)row * SEQ;
    bf16_t*      p = pr + (size_t)row * SEQ;
    int n   = q + 1;
    int tid = threadIdx.x;
    __shared__ float red[4];
    float lmax = -3.4e38f;
    for (int k = tid; k < n; k += 256) lmax = fmaxf(lmax, s[k]);
    for (int o = 32; o > 0; o >>= 1) lmax = fmaxf(lmax, __shfl_down(lmax, o, 64));
    if ((tid & 63) == 0) red[tid >> 6] = lmax;
    __syncthreads();
    float gmax = fmaxf(fmaxf(red[0], red[1]), fmaxf(red[2], red[3]));
    __syncthreads();
    float lsum = 0.f;
    for (int k = tid; k < n; k += 256) lsum += __expf(s[k] - gmax);
    for (int o = 32; o > 0; o >>= 1) lsum += __shfl_down(lsum, o, 64);
    if ((tid & 63) == 0) red[tid >> 6] = lsum;
    __syncthreads();
    float inv = 1.f / (red[0] + red[1] + red[2] + red[3]);
    for (int k = tid; k < SEQ; k += 256) {
        float v = (k < n) ? __expf(s[k] - gmax) * inv : 0.f;
        p[k] = (bf16_t)v;
    }
}

// ---------------- LayerNorm -> bf16 ----------------
__global__ void ln_kernel(const float* __restrict__ x, const float* __restrict__ g,
                          const float* __restrict__ b, bf16_t* __restrict__ o) {
    int row = blockIdx.x;
    int tid = threadIdx.x;
    const float* xr = x + (size_t)row * D_MODEL;
    int d = tid * 4;
    float4 v = *(const float4*)(xr + d);
    float s  = v.x + v.y + v.z + v.w;
    float s2 = v.x * v.x + v.y * v.y + v.z * v.z + v.w * v.w;
    __shared__ float rs[4], rs2[4];
    for (int of = 32; of > 0; of >>= 1) { s += __shfl_down(s, of, 64); s2 += __shfl_down(s2, of, 64); }
    if ((tid & 63) == 0) { rs[tid >> 6] = s; rs2[tid >> 6] = s2; }
    __syncthreads();
    float mean = (rs[0] + rs[1] + rs[2] + rs[3]) * (1.f / D_MODEL);
    float var  = (rs2[0] + rs2[1] + rs2[2] + rs2[3]) * (1.f / D_MODEL) - mean * mean;
    float rstd = rsqrtf(var + LN_EPS);
    float4 gg = *(const float4*)(g + d);
    float4 bb = *(const float4*)(b + d);
    union { bf16_t h[4]; unsigned long long u; } pk;
    pk.h[0] = (bf16_t)((v.x - mean) * rstd * gg.x + bb.x);
    pk.h[1] = (bf16_t)((v.y - mean) * rstd * gg.y + bb.y);
    pk.h[2] = (bf16_t)((v.z - mean) * rstd * gg.z + bb.z);
    pk.h[3] = (bf16_t)((v.w - mean) * rstd * gg.w + bb.w);
    *(unsigned long long*)(o + (size_t)row * D_MODEL + d) = pk.u;
}

// ---------------- host ----------------
extern "C" void kernel_launch(void* const* d_in, const int* in_sizes, int n_in,
                              void* d_out, int out_size, void* d_ws, size_t ws_size,
                              hipStream_t stream) {
    const int*   tokens  = (const int*)d_in[0];
    const float* tok_emb = (const float*)d_in[1];
    const float* pos_emb = (const float*)d_in[2];
    const float* Wq = (const float*)d_in[3];
    const float* bq = (const float*)d_in[4];
    const float* Wk = (const float*)d_in[5];
    const float* bk = (const float*)d_in[6];
    const float* Wv = (const float*)d_in[7];
    const float* bv = (const float*)d_in[8];
    const float* Wo = (const float*)d_in[9];
    const float* bo = (const float*)d_in[10];
    const float* Wup = (const float*)d_in[11];
    const float* bup = (const float*)d_in[12];
    const float* Wdn = (const float*)d_in[13];
    const float* bdn = (const float*)d_in[14];
    const float* ln_g = (const float*)d_in[15];
    const float* ln_b = (const float*)d_in[16];
    const float* Wu = (const float*)d_in[17];
    const float* bu = (const float*)d_in[18];
    float* out = (float*)d_out;

    (void)hipFuncSetAttribute((const void*)gemm256_kernel,
                              hipFuncAttributeMaxDynamicSharedMemorySize, 163840);
    (void)hipFuncSetAttribute((const void*)gemm256n_kernel,
                              hipFuncAttributeMaxDynamicSharedMemorySize, 114688);

    char* ws = (char*)d_ws;
    size_t off = 0;
    auto alloc = [&](size_t bytes) -> void* {
        void* p = ws + off; off += (bytes + 255) & ~(size_t)255; return p;
    };
    float*  x   = (float*)alloc((size_t)NTOK * D_MODEL * 4);
    bf16_t* xb  = (bf16_t*)alloc((size_t)NTOK * D_MODEL * 2);
    bf16_t* Qb  = (bf16_t*)alloc((size_t)NTOK * H_DIM * 2);
    bf16_t* Kb  = (bf16_t*)alloc((size_t)NTOK * H_DIM * 2);
    bf16_t* Vt  = (bf16_t*)alloc((size_t)NTOK * H_DIM * 2);   // [H][NTOK]
    float*  sc  = (float*)alloc((size_t)BATCH * SEQ * SEQ * 4);
    bf16_t* pr  = (bf16_t*)alloc((size_t)BATCH * SEQ * SEQ * 2);
    bf16_t* ao  = (bf16_t*)alloc((size_t)NTOK * H_DIM * 2);
    bf16_t* hb  = (bf16_t*)alloc((size_t)NTOK * H_DIM * 2);
    bf16_t* xln = (bf16_t*)alloc((size_t)NTOK * D_MODEL * 2);
    bf16_t* WT  = (bf16_t*)alloc((size_t)VOCAB * D_MODEL * 2); // reused weight buf

    auto gemm = [&](const bf16_t* A, const bf16_t* B, const float* bias, const float* resid,
                    float* Cf, bf16_t* Cb, int M, int N, int K, int ldb, int ldct,
                    float scale, int flags, long bsA = 0, long bsB = 0, long bsC = 0,
                    int gy = 1) {
        int nwg = (N / BN) * (M / BM);
        gemm_bf16_kernel<<<dim3(nwg, gy), 256, 0, stream>>>(A, B, bias, resid, Cf, Cb,
                                                            M, N, K, ldb, ldct, scale, flags,
                                                            bsA, bsB, bsC);
    };
    auto gemm256 = [&](const bf16_t* A, const bf16_t* B, const float* bias,
                       float* Cf, bf16_t* Cb, int M, int N, int K, int ldb, int ldct,
                       float scale, int flags, long bsA = 0, long bsB = 0, long bsC = 0,
                       int gy = 1) {
        int nwg = (N / 256) * (M / 256);
        gemm256_kernel<<<dim3(nwg, gy), 512, 163840, stream>>>(A, B, bias, Cf, Cb,
                                                               M, N, K, ldb, ldct, scale,
                                                               flags, bsA, bsB, bsC);
    };
    auto gemm256n = [&](const bf16_t* A, const bf16_t* B,
                        float* Cf, bf16_t* Cb, int M, int N, int K, int ldb,
                        float scale, int flags, long bsA, long bsB, long bsC, int gy) {
        int nwg = (N / 128) * (M / 256);
        gemm256n_kernel<<<dim3(nwg, gy), 512, 114688, stream>>>(A, B, Cf, Cb,
                                                                M, N, K, ldb, scale, flags,
                                                                bsA, bsB, bsC);
    };
    auto gemmnk = [&](const bf16_t* A, const bf16_t* B, const float* bias,
                      int M, int N, int K) {
        int nwg = (N / 64) * (M / 128);
        gemm_nk_kernel<<<nwg, 256, 0, stream>>>(A, B, bias, x, xb, M, N, K);
    };
    auto tcvt = [&](const float* W, bf16_t* T, int K, int N) {
        transpose_cvt_kernel<<<dim3(N / 32, K / 32), dim3(32, 8), 0, stream>>>(W, T, K, N);
    };

    embed_kernel<<<NTOK, 256, 0, stream>>>(tokens, tok_emb, pos_emb, x, xb);

    for (int l = 0; l < NBLK; ++l) {
        const float* wq = Wq + (size_t)l * D_MODEL * H_DIM;
        const float* wk = Wk + (size_t)l * D_MODEL * H_DIM;
        const float* wv = Wv + (size_t)l * D_MODEL * H_DIM;
        const float* wo = Wo + (size_t)l * H_DIM * D_MODEL;
        const float* wup = Wup + (size_t)l * D_MODEL * H_DIM;
        const float* wdn = Wdn + (size_t)l * H_DIM * D_MODEL;
        const float* bql = bq + (size_t)l * H_DIM;
        const float* bkl = bk + (size_t)l * H_DIM;
        const float* bvl = bv + (size_t)l * H_DIM;
        const float* bol = bo + (size_t)l * D_MODEL;
        const float* bupl = bup + (size_t)l * H_DIM;
        const float* bdnl = bdn + (size_t)l * D_MODEL;

        tcvt(wq, WT, D_MODEL, H_DIM);
        gemm256(xb, WT, bql, nullptr, Qb, NTOK, H_DIM, D_MODEL, D_MODEL, 0, 1.f, 0);
        tcvt(wk, WT, D_MODEL, H_DIM);
        gemm256(xb, WT, bkl, nullptr, Kb, NTOK, H_DIM, D_MODEL, D_MODEL, 0, 1.f, 0);
        tcvt(wv, WT, D_MODEL, H_DIM);
        gemm256(xb, WT, bvl, nullptr, Vt, NTOK, H_DIM, D_MODEL, D_MODEL, NTOK, 1.f, 8);

        // scores: both batches in one launch (blockIdx.y), swizzled 128^2 kernel
        gemm(Qb, Kb, nullptr, nullptr, sc, nullptr, SEQ, SEQ, H_DIM, H_DIM, 0,
             SCALE_QK, 2, (long)SEQ * H_DIM, (long)SEQ * H_DIM, (long)SEQ * SEQ, BATCH);

        softmax_kernel<<<NTOK, 256, 0, stream>>>(sc, pr);

        // attn@V: 256x128-tile variant — halves per-WG critical path (512 WGs)
        gemm256n(pr, Vt, nullptr, ao, SEQ, H_DIM, SEQ, NTOK,
                 1.f, 4, (long)SEQ * SEQ, (long)SEQ, (long)SEQ * H_DIM, BATCH);

        tcvt(wo, WT, H_DIM, D_MODEL);
        gemmnk(ao, WT, bol, NTOK, D_MODEL, H_DIM);

        tcvt(wup, WT, D_MODEL, H_DIM);
        gemm256(xb, WT, bupl, nullptr, hb, NTOK, H_DIM, D_MODEL, D_MODEL, 0, 1.f, 1);

        tcvt(wdn, WT, H_DIM, D_MODEL);
        gemmnk(hb, WT, bdnl, NTOK, D_MODEL, H_DIM);
    }

    ln_kernel<<<NTOK, 256, 0, stream>>>(x, ln_g, ln_b, xln);
    tcvt(Wu, WT, D_MODEL, VOCAB);
    gemm256(xln, WT, bu, out, nullptr, NTOK, VOCAB, D_MODEL, D_MODEL, 0, 1.f, 0);
}

// Round 15
// 2702.932 us; speedup vs baseline: 1.0603x; 1.0603x over previous
//
#include <hip/hip_runtime.h>
#include <hip/hip_bf16.h>

typedef __bf16 bf16_t;
typedef __attribute__((ext_vector_type(8))) __bf16 bf16x8;
typedef __attribute__((ext_vector_type(4))) float f32x4;

#define D_MODEL 1024
#define H_DIM   4096
#define VOCAB   32000
#define NBLK    4
#define BATCH   2
#define SEQ     2048
#define NTOK    (BATCH*SEQ)
#define SCALE_QK (1.0f/32.0f)
#define LN_EPS  1e-5f

#define BM 128
#define BN 128
#define BK 32
#define GROUP_M 8
#define NXCD 8

// async global->LDS, 16B per lane, LDS dest = wave-uniform base + lane*16
__device__ __forceinline__ void gload16(const bf16_t* g, bf16_t* l) {
    __builtin_amdgcn_global_load_lds(
        (const __attribute__((address_space(1))) void*)g,
        (__attribute__((address_space(3))) void*)l,
        16, 0, 0);
}

// ---------------- embedding: x = tok_emb[tok] + pos_emb[s] ----------------
__global__ void embed_kernel(const int* __restrict__ tokens,
                             const float* __restrict__ tok_emb,
                             const float* __restrict__ pos_emb,
                             float* __restrict__ x, bf16_t* __restrict__ xb) {
    int row = blockIdx.x;            // b*SEQ + s
    int s   = row & (SEQ - 1);
    int tok = tokens[row];
    const float* te = tok_emb + (size_t)tok * D_MODEL;
    const float* pe = pos_emb + (size_t)s * D_MODEL;
    int d = threadIdx.x * 4;         // 256 threads * 4 = 1024
    float4 a = *(const float4*)(te + d);
    float4 p = *(const float4*)(pe + d);
    float4 r; r.x = a.x + p.x; r.y = a.y + p.y; r.z = a.z + p.z; r.w = a.w + p.w;
    *(float4*)(x + (size_t)row * D_MODEL + d) = r;
    union { bf16_t h[4]; unsigned long long u; } pk;
    pk.h[0] = (bf16_t)r.x; pk.h[1] = (bf16_t)r.y; pk.h[2] = (bf16_t)r.z; pk.h[3] = (bf16_t)r.w;
    *(unsigned long long*)(xb + (size_t)row * D_MODEL + d) = pk.u;
}

// ---------------- transpose + fp32->bf16: WT[n][k] = W[k][n] ----------------
__global__ void transpose_cvt_kernel(const float* __restrict__ W, bf16_t* __restrict__ WT,
                                     int K, int N) {
    __shared__ float t[32][33];
    int k0 = blockIdx.y * 32, n0 = blockIdx.x * 32;
    int tx = threadIdx.x, ty = threadIdx.y;   // 32 x 8
    for (int i = ty; i < 32; i += 8) t[i][tx] = W[(size_t)(k0 + i) * N + n0 + tx];
    __syncthreads();
    for (int i = ty; i < 32; i += 8) WT[(size_t)(n0 + i) * K + k0 + tx] = (bf16_t)t[tx][i];
}

// ================= 256x256 8-wave pipelined GEMM, 4-phase schedule =================
// Race-fixed tail drain; batch via blockIdx.y; flag4 causal K-limit.
// flags: 1=relu, 4=causal K-limit, 8=store Cb transposed
__global__ __launch_bounds__(512)
void gemm256_kernel(const bf16_t* __restrict__ A, const bf16_t* __restrict__ B,
                    const float* __restrict__ bias,
                    float* __restrict__ Cf, bf16_t* __restrict__ Cb,
                    int M, int N, int K, int ldb, int ldct, float scale, int flags,
                    long bsA, long bsB, long bsC) {
    extern __shared__ char lds[];     // [0,64K): A slots 0/1; [64K,160K): B slots 0/1/2
    const int bidx = blockIdx.y;
    A += (size_t)bidx * bsA;
    B += (size_t)bidx * bsB;
    if (Cf) Cf += (size_t)bidx * bsC;
    if (Cb) Cb += (size_t)bidx * bsC;

    const int nTM = M >> 8, nTN = N >> 8;
    const int nwg = nTM * nTN;
    int orig = blockIdx.x;
    const int q = nwg / NXCD, r = nwg % NXCD;
    const int xcd = orig % NXCD, idx = orig / NXCD;
    int wgid = (xcd < r ? xcd * (q + 1) : r * (q + 1) + (xcd - r) * q) + idx;
    const int tpg = GROUP_M * nTN;
    const int g   = wgid / tpg;
    const int rem = wgid % tpg;
    int gm = nTM - g * GROUP_M; if (gm > GROUP_M) gm = GROUP_M;
    const int mt = g * GROUP_M + rem % gm;
    const int nt = rem / gm;
    const int m0 = mt << 8, n0 = nt << 8;
    const int Keff = (flags & 4) ? ((K < m0 + 256) ? K : (m0 + 256)) : K;

    const int tid  = threadIdx.x;
    const int lane = tid & 63;
    const int wid  = tid >> 6;
    const int wr   = wid >> 2;        // 0..1
    const int wc   = wid & 3;         // 0..3

    const int srow = tid >> 3;                         // 0..63
    const int scol = ((tid & 7) ^ (srow & 7)) << 3;    // element col, swizzled
    const bf16_t* Ag = A + (size_t)(m0 + srow) * K   + scol;
    const bf16_t* Bg = B + (size_t)(n0 + srow) * ldb + scol;
    char* ldsw = lds + wid * 1024;

    const int lr  = lane & 15;
    const int kgb = (lane >> 4) * 16;
    const int xv  = (lane & 7) << 4;
    const int aoff = (wr * 128 + lr) * 128;
    const int boff = (wc * 64  + lr) * 128;

    f32x4 acc[8][4];
#pragma unroll
    for (int i = 0; i < 8; ++i)
#pragma unroll
        for (int j = 0; j < 4; ++j) acc[i][j] = (f32x4){0.f, 0.f, 0.f, 0.f};

    const int NT = Keff >> 6;

    auto stageA = [&](int t) {
#pragma unroll
        for (int j = 0; j < 4; ++j)
            gload16(Ag + (size_t)j * 64 * K + t * 64,
                    (bf16_t*)(ldsw + (t & 1) * 32768 + j * 8192));
    };
    auto stageBj = [&](int t, int j) {
        gload16(Bg + (size_t)j * 64 * ldb + t * 64,
                (bf16_t*)(ldsw + 65536 + (t % 3) * 32768 + j * 8192));
    };

    stageBj(0,0); stageBj(0,1); stageBj(0,2); stageBj(0,3); stageA(0);
    if (NT > 1) { stageBj(1,0); stageBj(1,1); stageBj(1,2); stageBj(1,3); stageA(1); }
    asm volatile("s_waitcnt vmcnt(8)" ::: "memory");
    __builtin_amdgcn_s_barrier();

    for (int s = 0; s < NT; ++s) {
        const char* Abase = lds + (s & 1) * 32768 + aoff;
        const char* Bbase = lds + 65536 + (s % 3) * 32768 + boff;
        const bool pf = (s + 2 < NT);
        const int klo = kgb ^ xv;
        const int khi = (64 + kgb) ^ xv;

        bf16x8 av[4], aw[4], bv[4];

        // phase 0
#pragma unroll
        for (int i = 0; i < 4; ++i) av[i] = *(const bf16x8*)(Abase + i * 2048 + klo);
#pragma unroll
        for (int j = 0; j < 4; ++j) bv[j] = *(const bf16x8*)(Bbase + j * 2048 + klo);
        if (pf) { stageBj(s + 2, 0); stageBj(s + 2, 1); }
        __builtin_amdgcn_s_barrier();
        asm volatile("s_waitcnt lgkmcnt(0)" ::: "memory");
        __builtin_amdgcn_sched_barrier(0);
        __builtin_amdgcn_s_setprio(1);
#pragma unroll
        for (int i = 0; i < 4; ++i)
#pragma unroll
            for (int j = 0; j < 4; ++j)
                acc[i][j] = __builtin_amdgcn_mfma_f32_16x16x32_bf16(av[i], bv[j], acc[i][j], 0, 0, 0);
        __builtin_amdgcn_s_setprio(0);
        __builtin_amdgcn_s_barrier();

        // phase 1
#pragma unroll
        for (int i = 0; i < 4; ++i) aw[i] = *(const bf16x8*)(Abase + (4 + i) * 2048 + klo);
        if (pf) { stageBj(s + 2, 2); stageBj(s + 2, 3); }
        __builtin_amdgcn_s_barrier();
        asm volatile("s_waitcnt lgkmcnt(0)" ::: "memory");
        __builtin_amdgcn_sched_barrier(0);
        __builtin_amdgcn_s_setprio(1);
#pragma unroll
        for (int i = 0; i < 4; ++i)
#pragma unroll
            for (int j = 0; j < 4; ++j)
                acc[4 + i][j] = __builtin_amdgcn_mfma_f32_16x16x32_bf16(aw[i], bv[j], acc[4 + i][j], 0, 0, 0);
        __builtin_amdgcn_s_setprio(0);
        __builtin_amdgcn_s_barrier();

        // phase 2
#pragma unroll
        for (int i = 0; i < 4; ++i) av[i] = *(const bf16x8*)(Abase + i * 2048 + khi);
#pragma unroll
        for (int j = 0; j < 4; ++j) bv[j] = *(const bf16x8*)(Bbase + j * 2048 + khi);
        __builtin_amdgcn_s_barrier();
        asm volatile("s_waitcnt lgkmcnt(0)" ::: "memory");
        __builtin_amdgcn_sched_barrier(0);
        __builtin_amdgcn_s_setprio(1);
#pragma unroll
        for (int i = 0; i < 4; ++i)
#pragma unroll
            for (int j = 0; j < 4; ++j)
                acc[i][j] = __builtin_amdgcn_mfma_f32_16x16x32_bf16(av[i], bv[j], acc[i][j], 0, 0, 0);
        __builtin_amdgcn_s_setprio(0);
        __builtin_amdgcn_s_barrier();

        // phase 3
#pragma unroll
        for (int i = 0; i < 4; ++i) aw[i] = *(const bf16x8*)(Abase + (4 + i) * 2048 + khi);
        asm volatile("s_waitcnt lgkmcnt(0)" ::: "memory");
        __builtin_amdgcn_sched_barrier(0);
        __builtin_amdgcn_s_barrier();
        if (pf) stageA(s + 2);
        __builtin_amdgcn_s_setprio(1);
#pragma unroll
        for (int i = 0; i < 4; ++i)
#pragma unroll
            for (int j = 0; j < 4; ++j)
                acc[4 + i][j] = __builtin_amdgcn_mfma_f32_16x16x32_bf16(aw[i], bv[j], acc[4 + i][j], 0, 0, 0);
        __builtin_amdgcn_s_setprio(0);
        if (pf) asm volatile("s_waitcnt vmcnt(8)" ::: "memory");
        else    asm volatile("s_waitcnt vmcnt(0)" ::: "memory");
        __builtin_amdgcn_sched_barrier(0);
        __builtin_amdgcn_s_barrier();
    }

    const int r0 = (lane >> 4) * 4;
    const int cc = lane & 15;
#pragma unroll
    for (int i = 0; i < 8; ++i) {
        const int growb = m0 + wr * 128 + i * 16 + r0;
#pragma unroll
        for (int j = 0; j < 4; ++j) {
            const int gcol = n0 + wc * 64 + j * 16 + cc;
            const float bv2 = bias ? bias[gcol] : 0.f;
#pragma unroll
            for (int r2 = 0; r2 < 4; ++r2) {
                const int grow = growb + r2;
                float v = acc[i][j][r2] * scale + bv2;
                if (flags & 1) v = fmaxf(v, 0.f);
                if (Cf) Cf[(size_t)grow * N + gcol] = v;
                if (Cb) {
                    if (flags & 8) Cb[(size_t)gcol * ldct + grow] = (bf16_t)v;
                    else           Cb[(size_t)grow * N + gcol]   = (bf16_t)v;
                }
            }
        }
    }
}

// ---------------- generic bf16 GEMM, B in [N,K] layout (128^2, m97-class) ----------------
// batched via blockIdx.y; flags: 1=relu, 2=causal tile skip, 4=causal K-limit, 8=Cb transposed
__global__ __launch_bounds__(256)
void gemm_bf16_kernel(const bf16_t* __restrict__ A, const bf16_t* __restrict__ B,
                      const float* __restrict__ bias, const float* __restrict__ resid,
                      float* __restrict__ Cf, bf16_t* __restrict__ Cb,
                      int M, int N, int K, int ldb, int ldct, float scale, int flags,
                      long bsA, long bsB, long bsC) {
    const int bidx = blockIdx.y;
    A += (size_t)bidx * bsA;
    B += (size_t)bidx * bsB;
    if (Cf) Cf += (size_t)bidx * bsC;
    if (Cb) Cb += (size_t)bidx * bsC;

    const int nTM = M / BM, nTN = N / BN;
    const int nwg = nTM * nTN;
    int orig = blockIdx.x;
    const int q = nwg / NXCD, r = nwg % NXCD;
    const int xcd = orig % NXCD, idx = orig / NXCD;
    int wgid = (xcd < r ? xcd * (q + 1) : r * (q + 1) + (xcd - r) * q) + idx;
    const int tpg = GROUP_M * nTN;
    const int g   = wgid / tpg;
    const int rem = wgid % tpg;
    int gm = nTM - g * GROUP_M; if (gm > GROUP_M) gm = GROUP_M;
    const int mt = g * GROUP_M + rem % gm;
    const int nt = rem / gm;

    const int m0 = mt * BM;
    const int n0 = nt * BN;
    if ((flags & 2) && n0 > m0 + BM - 1) return;
    const int Keff = (flags & 4) ? ((K < m0 + BM) ? K : (m0 + BM)) : K;

    __shared__ bf16_t As[BM * BK];
    __shared__ bf16_t Bs[BN * BK];

    const int tid  = threadIdx.x;
    const int lane = tid & 63;
    const int wid  = tid >> 6;
    const int wr   = (wid >> 1) * 64;
    const int wc   = (wid & 1) * 64;

    f32x4 acc[4][4];
#pragma unroll
    for (int i = 0; i < 4; ++i)
#pragma unroll
        for (int j = 0; j < 4; ++j)
            acc[i][j] = (f32x4){0.f, 0.f, 0.f, 0.f};

    const int r_in = lane >> 2;
    const int c8   = ((lane & 3) ^ ((lane >> 3) & 3)) * 8;
    const bf16_t* Ap = A + (size_t)(m0 + wid * 32 + r_in) * K   + c8;
    const bf16_t* Bp = B + (size_t)(n0 + wid * 32 + r_in) * ldb + c8;
    bf16_t* AsW = As + wid * 1024;
    bf16_t* BsW = Bs + wid * 1024;

    const int rsel = lane & 15;
    const int kg   = ((lane >> 4) ^ ((rsel >> 1) & 3)) * 8;

    for (int k0 = 0; k0 < Keff; k0 += BK) {
        gload16(Ap + k0,                    AsW);
        gload16(Ap + k0 + (size_t)16 * K,   AsW + 512);
        gload16(Bp + k0,                    BsW);
        gload16(Bp + k0 + (size_t)16 * ldb, BsW + 512);
        __syncthreads();

        bf16x8 af[4], bfr[4];
#pragma unroll
        for (int i = 0; i < 4; ++i) {
            af[i]  = *(const bf16x8*)&As[(wr + i * 16 + rsel) * BK + kg];
            bfr[i] = *(const bf16x8*)&Bs[(wc + i * 16 + rsel) * BK + kg];
        }
#pragma unroll
        for (int i = 0; i < 4; ++i)
#pragma unroll
            for (int j = 0; j < 4; ++j)
                acc[i][j] = __builtin_amdgcn_mfma_f32_16x16x32_bf16(af[i], bfr[j], acc[i][j], 0, 0, 0);
        __syncthreads();
    }

    const int r0 = (lane >> 4) * 4;
    const int cc = lane & 15;
#pragma unroll
    for (int i = 0; i < 4; ++i) {
        const int growb = m0 + wr + i * 16 + r0;
#pragma unroll
        for (int j = 0; j < 4; ++j) {
            const int gcol = n0 + wc + j * 16 + cc;
            const float bv = bias ? bias[gcol] : 0.f;
#pragma unroll
            for (int r2 = 0; r2 < 4; ++r2) {
                const int grow = growb + r2;
                float v = acc[i][j][r2] * scale + bv;
                if (resid) v += resid[(size_t)grow * N + gcol];
                if (flags & 1) v = fmaxf(v, 0.f);
                if (Cf) Cf[(size_t)grow * N + gcol] = v;
                if (Cb) {
                    if (flags & 8) Cb[(size_t)gcol * ldct + grow] = (bf16_t)v;
                    else           Cb[(size_t)grow * N + gcol]   = (bf16_t)v;
                }
            }
        }
    }
}

// ---------------- narrow-N GEMM: 128x64 tile, BK=64 — Wo/Wdn ----------------
// 16 MFMA per barrier-pair (vs 8 at BK=32), 64 iterations at K=4096.
// LDS 24KB: As[128][64], Bs[64][64]; full 8-chunk XOR swizzle:
//   LDS[row][cd] holds global chunk cd ^ ((row>>1)&7)  (chunks of 8 elems = 16B)
// -> frag ds_read_b128: 16 lanes spread 8 chunks = 2-way/bank (free, m136).
// epilogue: v = acc + bias + x (residual); writes x (fp32) and xb (bf16).
__global__ __launch_bounds__(256)
void gemm_nk_kernel(const bf16_t* __restrict__ A, const bf16_t* __restrict__ B,
                    const float* __restrict__ bias,
                    float* __restrict__ x, bf16_t* __restrict__ xb,
                    int M, int N, int K) {
    const int nTM = M / 128, nTN = N / 64;
    const int nwg = nTM * nTN;
    int orig = blockIdx.x;
    const int q = nwg / NXCD, r = nwg % NXCD;
    const int xcd = orig % NXCD, idx = orig / NXCD;
    int wgid = (xcd < r ? xcd * (q + 1) : r * (q + 1) + (xcd - r) * q) + idx;
    const int tpg = GROUP_M * nTN;
    const int g   = wgid / tpg;
    const int rem = wgid % tpg;
    int gm = nTM - g * GROUP_M; if (gm > GROUP_M) gm = GROUP_M;
    const int mt = g * GROUP_M + rem % gm;
    const int nt = rem / gm;
    const int m0 = mt * 128;
    const int n0 = nt * 64;

    __shared__ bf16_t As[128 * 64];   // 16 KB, row stride 64 elems (128 B)
    __shared__ bf16_t Bs[64 * 64];    //  8 KB

    const int tid  = threadIdx.x;
    const int lane = tid & 63;
    const int wid  = tid >> 6;
    const int wr   = (wid >> 1) * 64;   // A row base
    const int wc   = (wid & 1) * 32;    // B row (=C col) base

    f32x4 acc[4][2];
#pragma unroll
    for (int i = 0; i < 4; ++i)
#pragma unroll
        for (int j = 0; j < 2; ++j)
            acc[i][j] = (f32x4){0.f, 0.f, 0.f, 0.f};

    // staging: segment s = 8 rows x 128B = 1024B, one wave-gload each.
    // A: 16 segs (4 calls x 4 waves); B: 8 segs (2 calls x 4 waves).
    // lane -> row-in-seg ri = lane>>3, dest chunk cd = lane&7;
    // source chunk = cd ^ ((row>>1)&7), row = seg*8 + ri.
    const int ri = lane >> 3;
    const int cd = lane & 7;

    // frag read: row = base16 + lr (base16 % 16 == 0) -> (row>>1)&7 = (lr>>1)&7
    const int lr  = lane & 15;
    const int gc  = lane >> 4;          // kgroup 0..3
    const int xk  = (lr >> 1) & 7;      // row-XOR for chunk

    for (int k0 = 0; k0 < K; k0 += 64) {
#pragma unroll
        for (int j = 0; j < 4; ++j) {       // A segments
            const int seg = j * 4 + wid;
            const int row = seg * 8 + ri;
            const int cs  = (cd ^ ((row >> 1) & 7)) * 8;
            gload16(A + (size_t)(m0 + row) * K + k0 + cs, As + seg * 512);
        }
#pragma unroll
        for (int j = 0; j < 2; ++j) {       // B segments
            const int seg = j * 4 + wid;
            const int row = seg * 8 + ri;
            const int cs  = (cd ^ ((row >> 1) & 7)) * 8;
            gload16(B + (size_t)(n0 + row) * K + k0 + cs, Bs + seg * 512);
        }
        __syncthreads();

#pragma unroll
        for (int half = 0; half < 2; ++half) {
            const int kc = ((gc + half * 4) ^ xk) * 8;   // swizzled chunk offset (elems)
            bf16x8 af[4], bfr[2];
#pragma unroll
            for (int i = 0; i < 4; ++i)
                af[i]  = *(const bf16x8*)&As[(wr + i * 16 + lr) * 64 + kc];
#pragma unroll
            for (int j = 0; j < 2; ++j)
                bfr[j] = *(const bf16x8*)&Bs[(wc + j * 16 + lr) * 64 + kc];
#pragma unroll
            for (int i = 0; i < 4; ++i)
#pragma unroll
                for (int j = 0; j < 2; ++j)
                    acc[i][j] = __builtin_amdgcn_mfma_f32_16x16x32_bf16(af[i], bfr[j], acc[i][j], 0, 0, 0);
        }
        __syncthreads();
    }

    const int r0 = (lane >> 4) * 4;
    const int cc = lane & 15;
#pragma unroll
    for (int i = 0; i < 4; ++i) {
        const int growb = m0 + wr + i * 16 + r0;
#pragma unroll
        for (int j = 0; j < 2; ++j) {
            const int gcol = n0 + wc + j * 16 + cc;
            const float bv = bias[gcol];
#pragma unroll
            for (int r2 = 0; r2 < 4; ++r2) {
                const int grow = growb + r2;
                const size_t off = (size_t)grow * N + gcol;
                float v = acc[i][j][r2] + bv + x[off];
                x[off]  = v;
                xb[off] = (bf16_t)v;
            }
        }
    }
}

// ---------------- causal softmax over k<=q, bf16 probs (zeros beyond) ----------------
__global__ void softmax_kernel(const float* __restrict__ sc, bf16_t* __restrict__ pr) {
    int row = blockIdx.x;                 // b*SEQ + q
    int q   = row & (SEQ - 1);
    const float* s = sc + (size_t)row * SEQ;
    bf16_t*      p = pr + (size_t)row * SEQ;
    int n   = q + 1;
    int tid = threadIdx.x;
    __shared__ float red[4];
    float lmax = -3.4e38f;
    for (int k = tid; k < n; k += 256) lmax = fmaxf(lmax, s[k]);
    for (int o = 32; o > 0; o >>= 1) lmax = fmaxf(lmax, __shfl_down(lmax, o, 64));
    if ((tid & 63) == 0) red[tid >> 6] = lmax;
    __syncthreads();
    float gmax = fmaxf(fmaxf(red[0], red[1]), fmaxf(red[2], red[3]));
    __syncthreads();
    float lsum = 0.f;
    for (int k = tid; k < n; k += 256) lsum += __expf(s[k] - gmax);
    for (int o = 32; o > 0; o >>= 1) lsum += __shfl_down(lsum, o, 64);
    if ((tid & 63) == 0) red[tid >> 6] = lsum;
    __syncthreads();
    float inv = 1.f / (red[0] + red[1] + red[2] + red[3]);
    for (int k = tid; k < SEQ; k += 256) {
        float v = (k < n) ? __expf(s[k] - gmax) * inv : 0.f;
        p[k] = (bf16_t)v;
    }
}

// ---------------- LayerNorm -> bf16 ----------------
__global__ void ln_kernel(const float* __restrict__ x, const float* __restrict__ g,
                          const float* __restrict__ b, bf16_t* __restrict__ o) {
    int row = blockIdx.x;
    int tid = threadIdx.x;
    const float* xr = x + (size_t)row * D_MODEL;
    int d = tid * 4;
    float4 v = *(const float4*)(xr + d);
    float s  = v.x + v.y + v.z + v.w;
    float s2 = v.x * v.x + v.y * v.y + v.z * v.z + v.w * v.w;
    __shared__ float rs[4], rs2[4];
    for (int of = 32; of > 0; of >>= 1) { s += __shfl_down(s, of, 64); s2 += __shfl_down(s2, of, 64); }
    if ((tid & 63) == 0) { rs[tid >> 6] = s; rs2[tid >> 6] = s2; }
    __syncthreads();
    float mean = (rs[0] + rs[1] + rs[2] + rs[3]) * (1.f / D_MODEL);
    float var  = (rs2[0] + rs2[1] + rs2[2] + rs2[3]) * (1.f / D_MODEL) - mean * mean;
    float rstd = rsqrtf(var + LN_EPS);
    float4 gg = *(const float4*)(g + d);
    float4 bb = *(const float4*)(b + d);
    union { bf16_t h[4]; unsigned long long u; } pk;
    pk.h[0] = (bf16_t)((v.x - mean) * rstd * gg.x + bb.x);
    pk.h[1] = (bf16_t)((v.y - mean) * rstd * gg.y + bb.y);
    pk.h[2] = (bf16_t)((v.z - mean) * rstd * gg.z + bb.z);
    pk.h[3] = (bf16_t)((v.w - mean) * rstd * gg.w + bb.w);
    *(unsigned long long*)(o + (size_t)row * D_MODEL + d) = pk.u;
}

// ---------------- host ----------------
extern "C" void kernel_launch(void* const* d_in, const int* in_sizes, int n_in,
                              void* d_out, int out_size, void* d_ws, size_t ws_size,
                              hipStream_t stream) {
    const int*   tokens  = (const int*)d_in[0];
    const float* tok_emb = (const float*)d_in[1];
    const float* pos_emb = (const float*)d_in[2];
    const float* Wq = (const float*)d_in[3];
    const float* bq = (const float*)d_in[4];
    const float* Wk = (const float*)d_in[5];
    const float* bk = (const float*)d_in[6];
    const float* Wv = (const float*)d_in[7];
    const float* bv = (const float*)d_in[8];
    const float* Wo = (const float*)d_in[9];
    const float* bo = (const float*)d_in[10];
    const float* Wup = (const float*)d_in[11];
    const float* bup = (const float*)d_in[12];
    const float* Wdn = (const float*)d_in[13];
    const float* bdn = (const float*)d_in[14];
    const float* ln_g = (const float*)d_in[15];
    const float* ln_b = (const float*)d_in[16];
    const float* Wu = (const float*)d_in[17];
    const float* bu = (const float*)d_in[18];
    float* out = (float*)d_out;

    (void)hipFuncSetAttribute((const void*)gemm256_kernel,
                              hipFuncAttributeMaxDynamicSharedMemorySize, 163840);

    char* ws = (char*)d_ws;
    size_t off = 0;
    auto alloc = [&](size_t bytes) -> void* {
        void* p = ws + off; off += (bytes + 255) & ~(size_t)255; return p;
    };
    float*  x   = (float*)alloc((size_t)NTOK * D_MODEL * 4);
    bf16_t* xb  = (bf16_t*)alloc((size_t)NTOK * D_MODEL * 2);
    bf16_t* Qb  = (bf16_t*)alloc((size_t)NTOK * H_DIM * 2);
    bf16_t* Kb  = (bf16_t*)alloc((size_t)NTOK * H_DIM * 2);
    bf16_t* Vt  = (bf16_t*)alloc((size_t)NTOK * H_DIM * 2);   // [H][NTOK]
    float*  sc  = (float*)alloc((size_t)BATCH * SEQ * SEQ * 4);
    bf16_t* pr  = (bf16_t*)alloc((size_t)BATCH * SEQ * SEQ * 2);
    bf16_t* ao  = (bf16_t*)alloc((size_t)NTOK * H_DIM * 2);
    bf16_t* hb  = (bf16_t*)alloc((size_t)NTOK * H_DIM * 2);
    bf16_t* xln = (bf16_t*)alloc((size_t)NTOK * D_MODEL * 2);
    bf16_t* WT  = (bf16_t*)alloc((size_t)VOCAB * D_MODEL * 2); // reused weight buf

    auto gemm = [&](const bf16_t* A, const bf16_t* B, const float* bias, const float* resid,
                    float* Cf, bf16_t* Cb, int M, int N, int K, int ldb, int ldct,
                    float scale, int flags, long bsA = 0, long bsB = 0, long bsC = 0,
                    int gy = 1) {
        int nwg = (N / BN) * (M / BM);
        gemm_bf16_kernel<<<dim3(nwg, gy), 256, 0, stream>>>(A, B, bias, resid, Cf, Cb,
                                                            M, N, K, ldb, ldct, scale, flags,
                                                            bsA, bsB, bsC);
    };
    auto gemm256 = [&](const bf16_t* A, const bf16_t* B, const float* bias,
                       float* Cf, bf16_t* Cb, int M, int N, int K, int ldb, int ldct,
                       float scale, int flags, long bsA = 0, long bsB = 0, long bsC = 0,
                       int gy = 1) {
        int nwg = (N / 256) * (M / 256);
        gemm256_kernel<<<dim3(nwg, gy), 512, 163840, stream>>>(A, B, bias, Cf, Cb,
                                                               M, N, K, ldb, ldct, scale,
                                                               flags, bsA, bsB, bsC);
    };
    auto gemmnk = [&](const bf16_t* A, const bf16_t* B, const float* bias,
                      int M, int N, int K) {
        int nwg = (N / 64) * (M / 128);
        gemm_nk_kernel<<<nwg, 256, 0, stream>>>(A, B, bias, x, xb, M, N, K);
    };
    auto tcvt = [&](const float* W, bf16_t* T, int K, int N) {
        transpose_cvt_kernel<<<dim3(N / 32, K / 32), dim3(32, 8), 0, stream>>>(W, T, K, N);
    };

    embed_kernel<<<NTOK, 256, 0, stream>>>(tokens, tok_emb, pos_emb, x, xb);

    for (int l = 0; l < NBLK; ++l) {
        const float* wq = Wq + (size_t)l * D_MODEL * H_DIM;
        const float* wk = Wk + (size_t)l * D_MODEL * H_DIM;
        const float* wv = Wv + (size_t)l * D_MODEL * H_DIM;
        const float* wo = Wo + (size_t)l * H_DIM * D_MODEL;
        const float* wup = Wup + (size_t)l * D_MODEL * H_DIM;
        const float* wdn = Wdn + (size_t)l * H_DIM * D_MODEL;
        const float* bql = bq + (size_t)l * H_DIM;
        const float* bkl = bk + (size_t)l * H_DIM;
        const float* bvl = bv + (size_t)l * H_DIM;
        const float* bol = bo + (size_t)l * D_MODEL;
        const float* bupl = bup + (size_t)l * H_DIM;
        const float* bdnl = bdn + (size_t)l * D_MODEL;

        tcvt(wq, WT, D_MODEL, H_DIM);
        gemm256(xb, WT, bql, nullptr, Qb, NTOK, H_DIM, D_MODEL, D_MODEL, 0, 1.f, 0);
        tcvt(wk, WT, D_MODEL, H_DIM);
        gemm256(xb, WT, bkl, nullptr, Kb, NTOK, H_DIM, D_MODEL, D_MODEL, 0, 1.f, 0);
        tcvt(wv, WT, D_MODEL, H_DIM);
        gemm256(xb, WT, bvl, nullptr, Vt, NTOK, H_DIM, D_MODEL, D_MODEL, NTOK, 1.f, 8);

        // scores: both batches in one launch (blockIdx.y), swizzled 128^2 kernel
        gemm(Qb, Kb, nullptr, nullptr, sc, nullptr, SEQ, SEQ, H_DIM, H_DIM, 0,
             SCALE_QK, 2, (long)SEQ * H_DIM, (long)SEQ * H_DIM, (long)SEQ * SEQ, BATCH);

        softmax_kernel<<<NTOK, 256, 0, stream>>>(sc, pr);

        // attn@V: gemm256, batched via blockIdx.y, causal Keff (flag 4) — round-13 best
        gemm256(pr, Vt, nullptr, nullptr, ao, SEQ, H_DIM, SEQ, NTOK, 0,
                1.f, 4, (long)SEQ * SEQ, (long)SEQ, (long)SEQ * H_DIM, BATCH);

        tcvt(wo, WT, H_DIM, D_MODEL);
        gemmnk(ao, WT, bol, NTOK, D_MODEL, H_DIM);

        tcvt(wup, WT, D_MODEL, H_DIM);
        gemm256(xb, WT, bupl, nullptr, hb, NTOK, H_DIM, D_MODEL, D_MODEL, 0, 1.f, 1);

        tcvt(wdn, WT, H_DIM, D_MODEL);
        gemmnk(hb, WT, bdnl, NTOK, D_MODEL, H_DIM);
    }

    ln_kernel<<<NTOK, 256, 0, stream>>>(x, ln_g, ln_b, xln);
    tcvt(Wu, WT, D_MODEL, VOCAB);
    gemm256(xln, WT, bu, out, nullptr, NTOK, VOCAB, D_MODEL, D_MODEL, 0, 1.f, 0);
}

// Round 16
// 2592.751 us; speedup vs baseline: 1.1053x; 1.0425x over previous
//
#include <hip/hip_runtime.h>
#include <hip/hip_bf16.h>

typedef __bf16 bf16_t;
typedef __attribute__((ext_vector_type(8))) __bf16 bf16x8;
typedef __attribute__((ext_vector_type(4))) float f32x4;

#define D_MODEL 1024
#define H_DIM   4096
#define VOCAB   32000
#define NBLK    4
#define BATCH   2
#define SEQ     2048
#define NTOK    (BATCH*SEQ)
#define SCALE_QK (1.0f/32.0f)
#define LN_EPS  1e-5f

#define BM 128
#define BN 128
#define GROUP_M 8
#define NXCD 8

// async global->LDS, 16B per lane, LDS dest = wave-uniform base + lane*16
__device__ __forceinline__ void gload16(const bf16_t* g, bf16_t* l) {
    __builtin_amdgcn_global_load_lds(
        (const __attribute__((address_space(1))) void*)g,
        (__attribute__((address_space(3))) void*)l,
        16, 0, 0);
}

// ---------------- embedding: x = tok_emb[tok] + pos_emb[s] ----------------
__global__ void embed_kernel(const int* __restrict__ tokens,
                             const float* __restrict__ tok_emb,
                             const float* __restrict__ pos_emb,
                             float* __restrict__ x, bf16_t* __restrict__ xb) {
    int row = blockIdx.x;            // b*SEQ + s
    int s   = row & (SEQ - 1);
    int tok = tokens[row];
    const float* te = tok_emb + (size_t)tok * D_MODEL;
    const float* pe = pos_emb + (size_t)s * D_MODEL;
    int d = threadIdx.x * 4;         // 256 threads * 4 = 1024
    float4 a = *(const float4*)(te + d);
    float4 p = *(const float4*)(pe + d);
    float4 r; r.x = a.x + p.x; r.y = a.y + p.y; r.z = a.z + p.z; r.w = a.w + p.w;
    *(float4*)(x + (size_t)row * D_MODEL + d) = r;
    union { bf16_t h[4]; unsigned long long u; } pk;
    pk.h[0] = (bf16_t)r.x; pk.h[1] = (bf16_t)r.y; pk.h[2] = (bf16_t)r.z; pk.h[3] = (bf16_t)r.w;
    *(unsigned long long*)(xb + (size_t)row * D_MODEL + d) = pk.u;
}

// ---------------- transpose + fp32->bf16: WT[n][k] = W[k][n] ----------------
__global__ void transpose_cvt_kernel(const float* __restrict__ W, bf16_t* __restrict__ WT,
                                     int K, int N) {
    __shared__ float t[32][33];
    int k0 = blockIdx.y * 32, n0 = blockIdx.x * 32;
    int tx = threadIdx.x, ty = threadIdx.y;   // 32 x 8
    for (int i = ty; i < 32; i += 8) t[i][tx] = W[(size_t)(k0 + i) * N + n0 + tx];
    __syncthreads();
    for (int i = ty; i < 32; i += 8) WT[(size_t)(n0 + i) * K + k0 + tx] = (bf16_t)t[tx][i];
}

// ================= 256x256 8-wave pipelined GEMM, 4-phase schedule =================
// Race-fixed tail drain; batch via blockIdx.y; flag4 causal K-limit.
// flags: 1=relu, 4=causal K-limit, 8=store Cb transposed
__global__ __launch_bounds__(512)
void gemm256_kernel(const bf16_t* __restrict__ A, const bf16_t* __restrict__ B,
                    const float* __restrict__ bias,
                    float* __restrict__ Cf, bf16_t* __restrict__ Cb,
                    int M, int N, int K, int ldb, int ldct, float scale, int flags,
                    long bsA, long bsB, long bsC) {
    extern __shared__ char lds[];     // [0,64K): A slots 0/1; [64K,160K): B slots 0/1/2
    const int bidx = blockIdx.y;
    A += (size_t)bidx * bsA;
    B += (size_t)bidx * bsB;
    if (Cf) Cf += (size_t)bidx * bsC;
    if (Cb) Cb += (size_t)bidx * bsC;

    const int nTM = M >> 8, nTN = N >> 8;
    const int nwg = nTM * nTN;
    int orig = blockIdx.x;
    const int q = nwg / NXCD, r = nwg % NXCD;
    const int xcd = orig % NXCD, idx = orig / NXCD;
    int wgid = (xcd < r ? xcd * (q + 1) : r * (q + 1) + (xcd - r) * q) + idx;
    const int tpg = GROUP_M * nTN;
    const int g   = wgid / tpg;
    const int rem = wgid % tpg;
    int gm = nTM - g * GROUP_M; if (gm > GROUP_M) gm = GROUP_M;
    const int mt = g * GROUP_M + rem % gm;
    const int nt = rem / gm;
    const int m0 = mt << 8, n0 = nt << 8;
    const int Keff = (flags & 4) ? ((K < m0 + 256) ? K : (m0 + 256)) : K;

    const int tid  = threadIdx.x;
    const int lane = tid & 63;
    const int wid  = tid >> 6;
    const int wr   = wid >> 2;        // 0..1
    const int wc   = wid & 3;         // 0..3

    const int srow = tid >> 3;                         // 0..63
    const int scol = ((tid & 7) ^ (srow & 7)) << 3;    // element col, swizzled
    const bf16_t* Ag = A + (size_t)(m0 + srow) * K   + scol;
    const bf16_t* Bg = B + (size_t)(n0 + srow) * ldb + scol;
    char* ldsw = lds + wid * 1024;

    const int lr  = lane & 15;
    const int kgb = (lane >> 4) * 16;
    const int xv  = (lane & 7) << 4;
    const int aoff = (wr * 128 + lr) * 128;
    const int boff = (wc * 64  + lr) * 128;

    f32x4 acc[8][4];
#pragma unroll
    for (int i = 0; i < 8; ++i)
#pragma unroll
        for (int j = 0; j < 4; ++j) acc[i][j] = (f32x4){0.f, 0.f, 0.f, 0.f};

    const int NT = Keff >> 6;

    auto stageA = [&](int t) {
#pragma unroll
        for (int j = 0; j < 4; ++j)
            gload16(Ag + (size_t)j * 64 * K + t * 64,
                    (bf16_t*)(ldsw + (t & 1) * 32768 + j * 8192));
    };
    auto stageBj = [&](int t, int j) {
        gload16(Bg + (size_t)j * 64 * ldb + t * 64,
                (bf16_t*)(ldsw + 65536 + (t % 3) * 32768 + j * 8192));
    };

    stageBj(0,0); stageBj(0,1); stageBj(0,2); stageBj(0,3); stageA(0);
    if (NT > 1) { stageBj(1,0); stageBj(1,1); stageBj(1,2); stageBj(1,3); stageA(1); }
    asm volatile("s_waitcnt vmcnt(8)" ::: "memory");
    __builtin_amdgcn_s_barrier();

    for (int s = 0; s < NT; ++s) {
        const char* Abase = lds + (s & 1) * 32768 + aoff;
        const char* Bbase = lds + 65536 + (s % 3) * 32768 + boff;
        const bool pf = (s + 2 < NT);
        const int klo = kgb ^ xv;
        const int khi = (64 + kgb) ^ xv;

        bf16x8 av[4], aw[4], bv[4];

        // phase 0
#pragma unroll
        for (int i = 0; i < 4; ++i) av[i] = *(const bf16x8*)(Abase + i * 2048 + klo);
#pragma unroll
        for (int j = 0; j < 4; ++j) bv[j] = *(const bf16x8*)(Bbase + j * 2048 + klo);
        if (pf) { stageBj(s + 2, 0); stageBj(s + 2, 1); }
        __builtin_amdgcn_s_barrier();
        asm volatile("s_waitcnt lgkmcnt(0)" ::: "memory");
        __builtin_amdgcn_sched_barrier(0);
        __builtin_amdgcn_s_setprio(1);
#pragma unroll
        for (int i = 0; i < 4; ++i)
#pragma unroll
            for (int j = 0; j < 4; ++j)
                acc[i][j] = __builtin_amdgcn_mfma_f32_16x16x32_bf16(av[i], bv[j], acc[i][j], 0, 0, 0);
        __builtin_amdgcn_s_setprio(0);
        __builtin_amdgcn_s_barrier();

        // phase 1
#pragma unroll
        for (int i = 0; i < 4; ++i) aw[i] = *(const bf16x8*)(Abase + (4 + i) * 2048 + klo);
        if (pf) { stageBj(s + 2, 2); stageBj(s + 2, 3); }
        __builtin_amdgcn_s_barrier();
        asm volatile("s_waitcnt lgkmcnt(0)" ::: "memory");
        __builtin_amdgcn_sched_barrier(0);
        __builtin_amdgcn_s_setprio(1);
#pragma unroll
        for (int i = 0; i < 4; ++i)
#pragma unroll
            for (int j = 0; j < 4; ++j)
                acc[4 + i][j] = __builtin_amdgcn_mfma_f32_16x16x32_bf16(aw[i], bv[j], acc[4 + i][j], 0, 0, 0);
        __builtin_amdgcn_s_setprio(0);
        __builtin_amdgcn_s_barrier();

        // phase 2
#pragma unroll
        for (int i = 0; i < 4; ++i) av[i] = *(const bf16x8*)(Abase + i * 2048 + khi);
#pragma unroll
        for (int j = 0; j < 4; ++j) bv[j] = *(const bf16x8*)(Bbase + j * 2048 + khi);
        __builtin_amdgcn_s_barrier();
        asm volatile("s_waitcnt lgkmcnt(0)" ::: "memory");
        __builtin_amdgcn_sched_barrier(0);
        __builtin_amdgcn_s_setprio(1);
#pragma unroll
        for (int i = 0; i < 4; ++i)
#pragma unroll
            for (int j = 0; j < 4; ++j)
                acc[i][j] = __builtin_amdgcn_mfma_f32_16x16x32_bf16(av[i], bv[j], acc[i][j], 0, 0, 0);
        __builtin_amdgcn_s_setprio(0);
        __builtin_amdgcn_s_barrier();

        // phase 3
#pragma unroll
        for (int i = 0; i < 4; ++i) aw[i] = *(const bf16x8*)(Abase + (4 + i) * 2048 + khi);
        asm volatile("s_waitcnt lgkmcnt(0)" ::: "memory");
        __builtin_amdgcn_sched_barrier(0);
        __builtin_amdgcn_s_barrier();
        if (pf) stageA(s + 2);
        __builtin_amdgcn_s_setprio(1);
#pragma unroll
        for (int i = 0; i < 4; ++i)
#pragma unroll
            for (int j = 0; j < 4; ++j)
                acc[4 + i][j] = __builtin_amdgcn_mfma_f32_16x16x32_bf16(aw[i], bv[j], acc[4 + i][j], 0, 0, 0);
        __builtin_amdgcn_s_setprio(0);
        if (pf) asm volatile("s_waitcnt vmcnt(8)" ::: "memory");
        else    asm volatile("s_waitcnt vmcnt(0)" ::: "memory");
        __builtin_amdgcn_sched_barrier(0);
        __builtin_amdgcn_s_barrier();
    }

    const int r0 = (lane >> 4) * 4;
    const int cc = lane & 15;
#pragma unroll
    for (int i = 0; i < 8; ++i) {
        const int growb = m0 + wr * 128 + i * 16 + r0;
#pragma unroll
        for (int j = 0; j < 4; ++j) {
            const int gcol = n0 + wc * 64 + j * 16 + cc;
            const float bv2 = bias ? bias[gcol] : 0.f;
#pragma unroll
            for (int r2 = 0; r2 < 4; ++r2) {
                const int grow = growb + r2;
                float v = acc[i][j][r2] * scale + bv2;
                if (flags & 1) v = fmaxf(v, 0.f);
                if (Cf) Cf[(size_t)grow * N + gcol] = v;
                if (Cb) {
                    if (flags & 8) Cb[(size_t)gcol * ldct + grow] = (bf16_t)v;
                    else           Cb[(size_t)grow * N + gcol]   = (bf16_t)v;
                }
            }
        }
    }
}

// ---------------- 128^2 GEMM, BK=64, full 8-chunk swizzle (scores path) ----------------
// Port of the round-15-verified gemmnk structure to 128x128: 32 MFMA per barrier-pair,
// LDS 32KB (As[128][64] + Bs[128][64]); LDS[row][cd] holds global chunk cd^((row>>1)&7).
// batched via blockIdx.y; flags: 1=relu, 2=causal tile skip, 4=causal K-limit, 8=Cb transposed
__global__ __launch_bounds__(256)
void gemm_bf16_kernel(const bf16_t* __restrict__ A, const bf16_t* __restrict__ B,
                      const float* __restrict__ bias, const float* __restrict__ resid,
                      float* __restrict__ Cf, bf16_t* __restrict__ Cb,
                      int M, int N, int K, int ldb, int ldct, float scale, int flags,
                      long bsA, long bsB, long bsC) {
    const int bidx = blockIdx.y;
    A += (size_t)bidx * bsA;
    B += (size_t)bidx * bsB;
    if (Cf) Cf += (size_t)bidx * bsC;
    if (Cb) Cb += (size_t)bidx * bsC;

    const int nTM = M / BM, nTN = N / BN;
    const int nwg = nTM * nTN;
    int orig = blockIdx.x;
    const int q = nwg / NXCD, r = nwg % NXCD;
    const int xcd = orig % NXCD, idx = orig / NXCD;
    int wgid = (xcd < r ? xcd * (q + 1) : r * (q + 1) + (xcd - r) * q) + idx;
    const int tpg = GROUP_M * nTN;
    const int g   = wgid / tpg;
    const int rem = wgid % tpg;
    int gm = nTM - g * GROUP_M; if (gm > GROUP_M) gm = GROUP_M;
    const int mt = g * GROUP_M + rem % gm;
    const int nt = rem / gm;

    const int m0 = mt * BM;
    const int n0 = nt * BN;
    if ((flags & 2) && n0 > m0 + BM - 1) return;
    const int Keff = (flags & 4) ? ((K < m0 + BM) ? K : (m0 + BM)) : K;

    __shared__ bf16_t As[128 * 64];   // 16 KB
    __shared__ bf16_t Bs[128 * 64];   // 16 KB

    const int tid  = threadIdx.x;
    const int lane = tid & 63;
    const int wid  = tid >> 6;
    const int wr   = (wid >> 1) * 64;
    const int wc   = (wid & 1) * 64;

    f32x4 acc[4][4];
#pragma unroll
    for (int i = 0; i < 4; ++i)
#pragma unroll
        for (int j = 0; j < 4; ++j)
            acc[i][j] = (f32x4){0.f, 0.f, 0.f, 0.f};

    // staging: 16 segs each (8 rows x 128B); lane -> row-in-seg lane>>3, dest chunk lane&7;
    // pre-swizzled source chunk = cd ^ ((row>>1)&7).
    const int ri = lane >> 3;
    const int cd = lane & 7;

    // frag read: row bases % 16 == 0 -> row-XOR = (lr>>1)&7
    const int lr = lane & 15;
    const int gc = lane >> 4;
    const int xk = (lr >> 1) & 7;

    for (int k0 = 0; k0 < Keff; k0 += 64) {
#pragma unroll
        for (int j = 0; j < 4; ++j) {       // A segments
            const int seg = j * 4 + wid;
            const int row = seg * 8 + ri;
            const int cs  = (cd ^ ((row >> 1) & 7)) * 8;
            gload16(A + (size_t)(m0 + row) * K + k0 + cs, As + seg * 512);
        }
#pragma unroll
        for (int j = 0; j < 4; ++j) {       // B segments
            const int seg = j * 4 + wid;
            const int row = seg * 8 + ri;
            const int cs  = (cd ^ ((row >> 1) & 7)) * 8;
            gload16(B + (size_t)(n0 + row) * ldb + k0 + cs, Bs + seg * 512);
        }
        __syncthreads();

#pragma unroll
        for (int half = 0; half < 2; ++half) {
            const int kc = ((gc + half * 4) ^ xk) * 8;
            bf16x8 af[4], bfr[4];
#pragma unroll
            for (int i = 0; i < 4; ++i) {
                af[i]  = *(const bf16x8*)&As[(wr + i * 16 + lr) * 64 + kc];
                bfr[i] = *(const bf16x8*)&Bs[(wc + i * 16 + lr) * 64 + kc];
            }
#pragma unroll
            for (int i = 0; i < 4; ++i)
#pragma unroll
                for (int j = 0; j < 4; ++j)
                    acc[i][j] = __builtin_amdgcn_mfma_f32_16x16x32_bf16(af[i], bfr[j], acc[i][j], 0, 0, 0);
        }
        __syncthreads();
    }

    const int r0 = (lane >> 4) * 4;
    const int cc = lane & 15;
#pragma unroll
    for (int i = 0; i < 4; ++i) {
        const int growb = m0 + wr + i * 16 + r0;
#pragma unroll
        for (int j = 0; j < 4; ++j) {
            const int gcol = n0 + wc + j * 16 + cc;
            const float bv = bias ? bias[gcol] : 0.f;
#pragma unroll
            for (int r2 = 0; r2 < 4; ++r2) {
                const int grow = growb + r2;
                float v = acc[i][j][r2] * scale + bv;
                if (resid) v += resid[(size_t)grow * N + gcol];
                if (flags & 1) v = fmaxf(v, 0.f);
                if (Cf) Cf[(size_t)grow * N + gcol] = v;
                if (Cb) {
                    if (flags & 8) Cb[(size_t)gcol * ldct + grow] = (bf16_t)v;
                    else           Cb[(size_t)grow * N + gcol]   = (bf16_t)v;
                }
            }
        }
    }
}

// ---------------- narrow-N GEMM: 128x64 tile, BK=64 — Wo/Wdn (round-15 verified) ----------
__global__ __launch_bounds__(256)
void gemm_nk_kernel(const bf16_t* __restrict__ A, const bf16_t* __restrict__ B,
                    const float* __restrict__ bias,
                    float* __restrict__ x, bf16_t* __restrict__ xb,
                    int M, int N, int K) {
    const int nTM = M / 128, nTN = N / 64;
    const int nwg = nTM * nTN;
    int orig = blockIdx.x;
    const int q = nwg / NXCD, r = nwg % NXCD;
    const int xcd = orig % NXCD, idx = orig / NXCD;
    int wgid = (xcd < r ? xcd * (q + 1) : r * (q + 1) + (xcd - r) * q) + idx;
    const int tpg = GROUP_M * nTN;
    const int g   = wgid / tpg;
    const int rem = wgid % tpg;
    int gm = nTM - g * GROUP_M; if (gm > GROUP_M) gm = GROUP_M;
    const int mt = g * GROUP_M + rem % gm;
    const int nt = rem / gm;
    const int m0 = mt * 128;
    const int n0 = nt * 64;

    __shared__ bf16_t As[128 * 64];   // 16 KB
    __shared__ bf16_t Bs[64 * 64];    //  8 KB

    const int tid  = threadIdx.x;
    const int lane = tid & 63;
    const int wid  = tid >> 6;
    const int wr   = (wid >> 1) * 64;   // A row base
    const int wc   = (wid & 1) * 32;    // B row (=C col) base

    f32x4 acc[4][2];
#pragma unroll
    for (int i = 0; i < 4; ++i)
#pragma unroll
        for (int j = 0; j < 2; ++j)
            acc[i][j] = (f32x4){0.f, 0.f, 0.f, 0.f};

    const int ri = lane >> 3;
    const int cd = lane & 7;
    const int lr  = lane & 15;
    const int gc  = lane >> 4;
    const int xk  = (lr >> 1) & 7;

    for (int k0 = 0; k0 < K; k0 += 64) {
#pragma unroll
        for (int j = 0; j < 4; ++j) {       // A segments
            const int seg = j * 4 + wid;
            const int row = seg * 8 + ri;
            const int cs  = (cd ^ ((row >> 1) & 7)) * 8;
            gload16(A + (size_t)(m0 + row) * K + k0 + cs, As + seg * 512);
        }
#pragma unroll
        for (int j = 0; j < 2; ++j) {       // B segments
            const int seg = j * 4 + wid;
            const int row = seg * 8 + ri;
            const int cs  = (cd ^ ((row >> 1) & 7)) * 8;
            gload16(B + (size_t)(n0 + row) * K + k0 + cs, Bs + seg * 512);
        }
        __syncthreads();

#pragma unroll
        for (int half = 0; half < 2; ++half) {
            const int kc = ((gc + half * 4) ^ xk) * 8;
            bf16x8 af[4], bfr[2];
#pragma unroll
            for (int i = 0; i < 4; ++i)
                af[i]  = *(const bf16x8*)&As[(wr + i * 16 + lr) * 64 + kc];
#pragma unroll
            for (int j = 0; j < 2; ++j)
                bfr[j] = *(const bf16x8*)&Bs[(wc + j * 16 + lr) * 64 + kc];
#pragma unroll
            for (int i = 0; i < 4; ++i)
#pragma unroll
                for (int j = 0; j < 2; ++j)
                    acc[i][j] = __builtin_amdgcn_mfma_f32_16x16x32_bf16(af[i], bfr[j], acc[i][j], 0, 0, 0);
        }
        __syncthreads();
    }

    const int r0 = (lane >> 4) * 4;
    const int cc = lane & 15;
#pragma unroll
    for (int i = 0; i < 4; ++i) {
        const int growb = m0 + wr + i * 16 + r0;
#pragma unroll
        for (int j = 0; j < 2; ++j) {
            const int gcol = n0 + wc + j * 16 + cc;
            const float bv = bias[gcol];
#pragma unroll
            for (int r2 = 0; r2 < 4; ++r2) {
                const int grow = growb + r2;
                const size_t off = (size_t)grow * N + gcol;
                float v = acc[i][j][r2] + bv + x[off];
                x[off]  = v;
                xb[off] = (bf16_t)v;
            }
        }
    }
}

// ---------------- causal softmax over k<=q, bf16 probs (zeros beyond) ----------------
__global__ void softmax_kernel(const float* __restrict__ sc, bf16_t* __restrict__ pr) {
    int row = blockIdx.x;                 // b*SEQ + q
    int q   = row & (SEQ - 1);
    const float* s = sc + (size_t)row * SEQ;
    bf16_t*      p = pr + (size_t)row * SEQ;
    int n   = q + 1;
    int tid = threadIdx.x;
    __shared__ float red[4];
    float lmax = -3.4e38f;
    for (int k = tid; k < n; k += 256) lmax = fmaxf(lmax, s[k]);
    for (int o = 32; o > 0; o >>= 1) lmax = fmaxf(lmax, __shfl_down(lmax, o, 64));
    if ((tid & 63) == 0) red[tid >> 6] = lmax;
    __syncthreads();
    float gmax = fmaxf(fmaxf(red[0], red[1]), fmaxf(red[2], red[3]));
    __syncthreads();
    float lsum = 0.f;
    for (int k = tid; k < n; k += 256) lsum += __expf(s[k] - gmax);
    for (int o = 32; o > 0; o >>= 1) lsum += __shfl_down(lsum, o, 64);
    if ((tid & 63) == 0) red[tid >> 6] = lsum;
    __syncthreads();
    float inv = 1.f / (red[0] + red[1] + red[2] + red[3]);
    for (int k = tid; k < SEQ; k += 256) {
        float v = (k < n) ? __expf(s[k] - gmax) * inv : 0.f;
        p[k] = (bf16_t)v;
    }
}

// ---------------- LayerNorm -> bf16 ----------------
__global__ void ln_kernel(const float* __restrict__ x, const float* __restrict__ g,
                          const float* __restrict__ b, bf16_t* __restrict__ o) {
    int row = blockIdx.x;
    int tid = threadIdx.x;
    const float* xr = x + (size_t)row * D_MODEL;
    int d = tid * 4;
    float4 v = *(const float4*)(xr + d);
    float s  = v.x + v.y + v.z + v.w;
    float s2 = v.x * v.x + v.y * v.y + v.z * v.z + v.w * v.w;
    __shared__ float rs[4], rs2[4];
    for (int of = 32; of > 0; of >>= 1) { s += __shfl_down(s, of, 64); s2 += __shfl_down(s2, of, 64); }
    if ((tid & 63) == 0) { rs[tid >> 6] = s; rs2[tid >> 6] = s2; }
    __syncthreads();
    float mean = (rs[0] + rs[1] + rs[2] + rs[3]) * (1.f / D_MODEL);
    float var  = (rs2[0] + rs2[1] + rs2[2] + rs2[3]) * (1.f / D_MODEL) - mean * mean;
    float rstd = rsqrtf(var + LN_EPS);
    float4 gg = *(const float4*)(g + d);
    float4 bb = *(const float4*)(b + d);
    union { bf16_t h[4]; unsigned long long u; } pk;
    pk.h[0] = (bf16_t)((v.x - mean) * rstd * gg.x + bb.x);
    pk.h[1] = (bf16_t)((v.y - mean) * rstd * gg.y + bb.y);
    pk.h[2] = (bf16_t)((v.z - mean) * rstd * gg.z + bb.z);
    pk.h[3] = (bf16_t)((v.w - mean) * rstd * gg.w + bb.w);
    *(unsigned long long*)(o + (size_t)row * D_MODEL + d) = pk.u;
}

// ---------------- host ----------------
extern "C" void kernel_launch(void* const* d_in, const int* in_sizes, int n_in,
                              void* d_out, int out_size, void* d_ws, size_t ws_size,
                              hipStream_t stream) {
    const int*   tokens  = (const int*)d_in[0];
    const float* tok_emb = (const float*)d_in[1];
    const float* pos_emb = (const float*)d_in[2];
    const float* Wq = (const float*)d_in[3];
    const float* bq = (const float*)d_in[4];
    const float* Wk = (const float*)d_in[5];
    const float* bk = (const float*)d_in[6];
    const float* Wv = (const float*)d_in[7];
    const float* bv = (const float*)d_in[8];
    const float* Wo = (const float*)d_in[9];
    const float* bo = (const float*)d_in[10];
    const float* Wup = (const float*)d_in[11];
    const float* bup = (const float*)d_in[12];
    const float* Wdn = (const float*)d_in[13];
    const float* bdn = (const float*)d_in[14];
    const float* ln_g = (const float*)d_in[15];
    const float* ln_b = (const float*)d_in[16];
    const float* Wu = (const float*)d_in[17];
    const float* bu = (const float*)d_in[18];
    float* out = (float*)d_out;

    (void)hipFuncSetAttribute((const void*)gemm256_kernel,
                              hipFuncAttributeMaxDynamicSharedMemorySize, 163840);

    char* ws = (char*)d_ws;
    size_t off = 0;
    auto alloc = [&](size_t bytes) -> void* {
        void* p = ws + off; off += (bytes + 255) & ~(size_t)255; return p;
    };
    float*  x   = (float*)alloc((size_t)NTOK * D_MODEL * 4);
    bf16_t* xb  = (bf16_t*)alloc((size_t)NTOK * D_MODEL * 2);
    bf16_t* Qb  = (bf16_t*)alloc((size_t)NTOK * H_DIM * 2);
    bf16_t* Kb  = (bf16_t*)alloc((size_t)NTOK * H_DIM * 2);
    bf16_t* Vt  = (bf16_t*)alloc((size_t)NTOK * H_DIM * 2);   // [H][NTOK]
    float*  sc  = (float*)alloc((size_t)BATCH * SEQ * SEQ * 4);
    bf16_t* pr  = (bf16_t*)alloc((size_t)BATCH * SEQ * SEQ * 2);
    bf16_t* ao  = (bf16_t*)alloc((size_t)NTOK * H_DIM * 2);
    bf16_t* hb  = (bf16_t*)alloc((size_t)NTOK * H_DIM * 2);
    bf16_t* xln = (bf16_t*)alloc((size_t)NTOK * D_MODEL * 2);
    bf16_t* WT  = (bf16_t*)alloc((size_t)VOCAB * D_MODEL * 2); // reused weight buf

    auto gemm = [&](const bf16_t* A, const bf16_t* B, const float* bias, const float* resid,
                    float* Cf, bf16_t* Cb, int M, int N, int K, int ldb, int ldct,
                    float scale, int flags, long bsA = 0, long bsB = 0, long bsC = 0,
                    int gy = 1) {
        int nwg = (N / BN) * (M / BM);
        gemm_bf16_kernel<<<dim3(nwg, gy), 256, 0, stream>>>(A, B, bias, resid, Cf, Cb,
                                                            M, N, K, ldb, ldct, scale, flags,
                                                            bsA, bsB, bsC);
    };
    auto gemm256 = [&](const bf16_t* A, const bf16_t* B, const float* bias,
                       float* Cf, bf16_t* Cb, int M, int N, int K, int ldb, int ldct,
                       float scale, int flags, long bsA = 0, long bsB = 0, long bsC = 0,
                       int gy = 1) {
        int nwg = (N / 256) * (M / 256);
        gemm256_kernel<<<dim3(nwg, gy), 512, 163840, stream>>>(A, B, bias, Cf, Cb,
                                                               M, N, K, ldb, ldct, scale,
                                                               flags, bsA, bsB, bsC);
    };
    auto gemmnk = [&](const bf16_t* A, const bf16_t* B, const float* bias,
                      int M, int N, int K) {
        int nwg = (N / 64) * (M / 128);
        gemm_nk_kernel<<<nwg, 256, 0, stream>>>(A, B, bias, x, xb, M, N, K);
    };
    auto tcvt = [&](const float* W, bf16_t* T, int K, int N) {
        transpose_cvt_kernel<<<dim3(N / 32, K / 32), dim3(32, 8), 0, stream>>>(W, T, K, N);
    };

    embed_kernel<<<NTOK, 256, 0, stream>>>(tokens, tok_emb, pos_emb, x, xb);

    for (int l = 0; l < NBLK; ++l) {
        const float* wq = Wq + (size_t)l * D_MODEL * H_DIM;
        const float* wk = Wk + (size_t)l * D_MODEL * H_DIM;
        const float* wv = Wv + (size_t)l * D_MODEL * H_DIM;
        const float* wo = Wo + (size_t)l * H_DIM * D_MODEL;
        const float* wup = Wup + (size_t)l * D_MODEL * H_DIM;
        const float* wdn = Wdn + (size_t)l * H_DIM * D_MODEL;
        const float* bql = bq + (size_t)l * H_DIM;
        const float* bkl = bk + (size_t)l * H_DIM;
        const float* bvl = bv + (size_t)l * H_DIM;
        const float* bol = bo + (size_t)l * D_MODEL;
        const float* bupl = bup + (size_t)l * H_DIM;
        const float* bdnl = bdn + (size_t)l * D_MODEL;

        tcvt(wq, WT, D_MODEL, H_DIM);
        gemm256(xb, WT, bql, nullptr, Qb, NTOK, H_DIM, D_MODEL, D_MODEL, 0, 1.f, 0);
        tcvt(wk, WT, D_MODEL, H_DIM);
        gemm256(xb, WT, bkl, nullptr, Kb, NTOK, H_DIM, D_MODEL, D_MODEL, 0, 1.f, 0);
        tcvt(wv, WT, D_MODEL, H_DIM);
        gemm256(xb, WT, bvl, nullptr, Vt, NTOK, H_DIM, D_MODEL, D_MODEL, NTOK, 1.f, 8);

        // scores: both batches in one launch (blockIdx.y), BK=64 swizzled 128^2 kernel
        gemm(Qb, Kb, nullptr, nullptr, sc, nullptr, SEQ, SEQ, H_DIM, H_DIM, 0,
             SCALE_QK, 2, (long)SEQ * H_DIM, (long)SEQ * H_DIM, (long)SEQ * SEQ, BATCH);

        softmax_kernel<<<NTOK, 256, 0, stream>>>(sc, pr);

        // attn@V: gemm256, batched via blockIdx.y, causal Keff (flag 4) — round-13 best
        gemm256(pr, Vt, nullptr, nullptr, ao, SEQ, H_DIM, SEQ, NTOK, 0,
                1.f, 4, (long)SEQ * SEQ, (long)SEQ, (long)SEQ * H_DIM, BATCH);

        tcvt(wo, WT, H_DIM, D_MODEL);
        gemmnk(ao, WT, bol, NTOK, D_MODEL, H_DIM);

        tcvt(wup, WT, D_MODEL, H_DIM);
        gemm256(xb, WT, bupl, nullptr, hb, NTOK, H_DIM, D_MODEL, D_MODEL, 0, 1.f, 1);

        tcvt(wdn, WT, H_DIM, D_MODEL);
        gemmnk(hb, WT, bdnl, NTOK, D_MODEL, H_DIM);
    }

    ln_kernel<<<NTOK, 256, 0, stream>>>(x, ln_g, ln_b, xln);
    tcvt(Wu, WT, D_MODEL, VOCAB);
    gemm256(xln, WT, bu, out, nullptr, NTOK, VOCAB, D_MODEL, D_MODEL, 0, 1.f, 0);
}